// Round 3
// baseline (1180.461 us; speedup 1.0000x reference)
//
#include <hip/hip_runtime.h>
#include <hip/hip_fp16.h>
#include <stdint.h>

#define N_NODES 100000
#define N_EDGES 640000
#define R_REL   64
#define D_DIM   128
#define L_LAYERS 2

#define SCAN_CHUNK 1024
#define NBLK_SCAN ((N_NODES + SCAN_CHUNK - 1) / SCAN_CHUNK)   // 98

#define LDA 136   // bf16 A-tile stride (128 + 8 pad)
#define LDT 264   // bf16 t-tile stride (256 + 8 pad)
#define LDF 132   // f32 accumulator tile stride (128 + 4 pad)
#define ECAP 512  // staged edges per block (int2, 4096 B)

typedef __attribute__((ext_vector_type(8))) short   short8;   // 8 bf16 MFMA frag
typedef __attribute__((ext_vector_type(4))) unsigned short ushort4v;
typedef __attribute__((ext_vector_type(4))) unsigned int   uint4v;
typedef __attribute__((ext_vector_type(4))) float   f32x4;

__device__ __forceinline__ unsigned short f32_to_bf16(float f) {
  union { float f; uint32_t u; } v; v.f = f;
  uint32_t u = v.u;
  u += 0x7fffu + ((u >> 16) & 1u);   // RNE (finite inputs only)
  return (unsigned short)(u >> 16);
}
__device__ __forceinline__ unsigned short f2h(float f) {
  __half h = __float2half(f);
  return __half_as_ushort(h);
}
__device__ __forceinline__ __half2 u2h(unsigned int u) {
  union { unsigned int u; __half2 h; } v; v.u = u; return v.h;
}

// ---------------------------------------------------------------------------
// CSR build: histogram -> 3-kernel exclusive scan -> slot scatter
// ---------------------------------------------------------------------------
__global__ __launch_bounds__(256)
void hist_kernel(const int* __restrict__ ei, int* __restrict__ deg) {
  int idx = blockIdx.x * 256 + threadIdx.x;
  atomicAdd(&deg[ei[N_EDGES + idx]], 1);
}

__global__ __launch_bounds__(256)
void scan_part1(const int* __restrict__ deg, int* __restrict__ partial) {
  __shared__ int lds[256];
  const int b = blockIdx.x, t = threadIdx.x;
  const int base = b * SCAN_CHUNK + t * 4;
  int s = 0;
  for (int k = 0; k < 4; ++k) { int i = base + k; s += (i < N_NODES) ? deg[i] : 0; }
  lds[t] = s; __syncthreads();
  for (int off = 128; off > 0; off >>= 1) {
    if (t < off) lds[t] += lds[t + off];
    __syncthreads();
  }
  if (t == 0) partial[b] = lds[0];
}

__global__ __launch_bounds__(128)
void scan_part2(int* __restrict__ partial, int* __restrict__ blockoff) {
  __shared__ int lds[128];
  const int t = threadIdx.x;
  const int v = (t < NBLK_SCAN) ? partial[t] : 0;
  lds[t] = v; __syncthreads();
  for (int off = 1; off < 128; off <<= 1) {
    int add = (t >= off) ? lds[t - off] : 0;
    __syncthreads();
    lds[t] += add;
    __syncthreads();
  }
  if (t < NBLK_SCAN) blockoff[t] = lds[t] - v;   // exclusive
}

__global__ __launch_bounds__(256)
void scan_part3(const int* __restrict__ deg, const int* __restrict__ blockoff,
                int* __restrict__ rowptr, int* __restrict__ cursor) {
  __shared__ int lds[256];
  const int b = blockIdx.x, t = threadIdx.x;
  const int base = b * SCAN_CHUNK + t * 4;
  int v[4]; int s = 0;
  for (int k = 0; k < 4; ++k) {
    int i = base + k;
    v[k] = (i < N_NODES) ? deg[i] : 0;
    s += v[k];
  }
  lds[t] = s; __syncthreads();
  for (int off = 1; off < 256; off <<= 1) {
    int add = (t >= off) ? lds[t - off] : 0;
    __syncthreads();
    lds[t] += add;
    __syncthreads();
  }
  int excl = lds[t] - s + blockoff[b];
  for (int k = 0; k < 4; ++k) {
    int i = base + k;
    if (i < N_NODES) { rowptr[i] = excl; cursor[i] = excl; excl += v[k]; }
  }
  if (b == 0 && t == 0) rowptr[N_NODES] = N_EDGES;
}

__global__ __launch_bounds__(256)
void scatter_kernel(const int* __restrict__ ei, const int* __restrict__ et,
                    int* __restrict__ cursor, int2* __restrict__ edges2) {
  int idx = blockIdx.x * 256 + threadIdx.x;
  int dst = ei[N_EDGES + idx];
  int slot = atomicAdd(&cursor[dst], 1);
  edges2[slot] = make_int2(ei[idx], et[idx]);
}

// ---------------------------------------------------------------------------
// prep: blocks [0,128): gamma/beta -> packed f16 gbb.
//       blocks [128,384): weight f32->bf16 conversion (MFMA weights).
// gbb layout per type t (256 f16): group s (0..31) holds 8 halfs:
//   { g[2s], g[2s+1], b[2s], b[2s+1], g[2s+64], g[2s+65], b[2s+64], b[2s+65] }
// so one 16B load + two __hfma2 covers lane s's 4 columns {2s,2s+1,2s+64,2s+65}.
// ---------------------------------------------------------------------------
__global__ __launch_bounds__(256)
void prep_kernel(const float* __restrict__ rel_emb,
                 const float* __restrict__ rmw0, const float* __restrict__ rmb0,
                 const float* __restrict__ rmw1, const float* __restrict__ rmb1,
                 const float* __restrict__ rmw2, const float* __restrict__ rmb2,
                 const float* __restrict__ rmw3, const float* __restrict__ rmb3,
                 unsigned short* __restrict__ gbb,
                 const float* __restrict__ Ww, const float* __restrict__ mw0,
                 const float* __restrict__ mw1,
                 unsigned short* __restrict__ Wwb, unsigned short* __restrict__ mw0b,
                 unsigned short* __restrict__ mw1b) {
  if (blockIdx.x >= 128) {
    int i = (blockIdx.x - 128) * 256 + threadIdx.x;   // 0..65535
    if (i < L_LAYERS * D_DIM * D_DIM)     Wwb[i]  = f32_to_bf16(Ww[i]);
    if (i < L_LAYERS * 2 * D_DIM * D_DIM) mw0b[i] = f32_to_bf16(mw0[i]);
    if (i < L_LAYERS * 2 * D_DIM * D_DIM) mw1b[i] = f32_to_bf16(mw1[i]);
    return;
  }
  __shared__ float bufA[2 * D_DIM];
  __shared__ float bufB[2 * D_DIM];
  const int l = blockIdx.x >> 6;
  const int r = blockIdx.x & 63;
  const int j = threadIdx.x;   // 0..255

  if (j < D_DIM) bufA[j] = rel_emb[(l * R_REL + r) * D_DIM + j];
  __syncthreads();
  {
    const float* w = rmw0 + ((size_t)l * 2 * D_DIM + j) * D_DIM;
    float s = rmb0[l * 2 * D_DIM + j];
    for (int k = 0; k < D_DIM; k += 4) {
      float4 wv = *(const float4*)(w + k);
      s += wv.x * bufA[k] + wv.y * bufA[k + 1] + wv.z * bufA[k + 2] + wv.w * bufA[k + 3];
    }
    bufB[j] = fmaxf(s, 0.0f);
  }
  __syncthreads();
  {
    const float* w = rmw1 + ((size_t)l * 2 * D_DIM + j) * 2 * D_DIM;
    float s = rmb1[l * 2 * D_DIM + j];
    for (int k = 0; k < 2 * D_DIM; k += 4) {
      float4 wv = *(const float4*)(w + k);
      s += wv.x * bufB[k] + wv.y * bufB[k + 1] + wv.z * bufB[k + 2] + wv.w * bufB[k + 3];
    }
    __syncthreads();
    bufA[j] = fmaxf(s, 0.0f);
  }
  __syncthreads();
  {
    const float* w = rmw2 + ((size_t)l * 2 * D_DIM + j) * 2 * D_DIM;
    float s = rmb2[l * 2 * D_DIM + j];
    for (int k = 0; k < 2 * D_DIM; k += 4) {
      float4 wv = *(const float4*)(w + k);
      s += wv.x * bufA[k] + wv.y * bufA[k + 1] + wv.z * bufA[k + 2] + wv.w * bufA[k + 3];
    }
    __syncthreads();
    bufB[j] = fmaxf(s, 0.0f);
  }
  __syncthreads();
  {
    const float* w = rmw3 + ((size_t)l * 2 * D_DIM + j) * 2 * D_DIM;
    float s = rmb3[l * 2 * D_DIM + j];
    for (int k = 0; k < 2 * D_DIM; k += 4) {
      float4 wv = *(const float4*)(w + k);
      s += wv.x * bufB[k] + wv.y * bufB[k + 1] + wv.z * bufB[k + 2] + wv.w * bufB[k + 3];
    }
    const int t = l * R_REL + r;
    if (j < D_DIM) {            // gamma col j
      int idx = ((j & 63) >> 1) * 8 + ((j >> 6) << 2) + (j & 1);
      gbb[t * 256 + idx] = f2h(s);
    } else {                    // beta col j-128
      int c = j - D_DIM;
      int idx = ((c & 63) >> 1) * 8 + ((c >> 6) << 2) + (c & 1) + 2;
      gbb[t * 256 + idx] = f2h(s);
    }
  }
}

// ---------------------------------------------------------------------------
// xw = f16( x @ Ww^T + Wb )  (N x 128). bf16 MFMA weights, f16 output.
// ---------------------------------------------------------------------------
__global__ __launch_bounds__(256)
void xw_kernel(const float* __restrict__ x,
               const unsigned short* __restrict__ Wwb,  // 128x128 bf16 layer slice
               const float* __restrict__ Wb,            // 128
               unsigned short* __restrict__ xwb) {      // f16 bits out
  __shared__ unsigned short a_lds[32 * LDA];
  const int tid = threadIdx.x;
  const int m0 = blockIdx.x * 32;

  for (int i = tid; i < 1024; i += 256) {
    int row = i >> 5, ch = i & 31;
    float4 v = *(const float4*)&x[(m0 + row) * D_DIM + ch * 4];
    ushort4v s;
    s[0] = f32_to_bf16(v.x); s[1] = f32_to_bf16(v.y);
    s[2] = f32_to_bf16(v.z); s[3] = f32_to_bf16(v.w);
    *(ushort4v*)&a_lds[row * LDA + ch * 4] = s;
  }
  __syncthreads();

  const int wave = tid >> 6, lane = tid & 63;
  const int lrow = lane & 15, quad = lane >> 4;
  const int n0 = wave * 32;

  f32x4 acc[2][2] = {};
  for (int ks = 0; ks < 128; ks += 32) {
    short8 a0 = *(const short8*)&a_lds[lrow * LDA + ks + quad * 8];
    short8 a1 = *(const short8*)&a_lds[(16 + lrow) * LDA + ks + quad * 8];
    short8 b0 = *(const short8*)&Wwb[(n0 + lrow) * D_DIM + ks + quad * 8];
    short8 b1 = *(const short8*)&Wwb[(n0 + 16 + lrow) * D_DIM + ks + quad * 8];
    acc[0][0] = __builtin_amdgcn_mfma_f32_16x16x32_bf16(a0, b0, acc[0][0], 0, 0, 0);
    acc[0][1] = __builtin_amdgcn_mfma_f32_16x16x32_bf16(a0, b1, acc[0][1], 0, 0, 0);
    acc[1][0] = __builtin_amdgcn_mfma_f32_16x16x32_bf16(a1, b0, acc[1][0], 0, 0, 0);
    acc[1][1] = __builtin_amdgcn_mfma_f32_16x16x32_bf16(a1, b1, acc[1][1], 0, 0, 0);
  }

  for (int mt = 0; mt < 2; ++mt)
    for (int nt = 0; nt < 2; ++nt)
      for (int rr = 0; rr < 4; ++rr) {
        int row = mt * 16 + quad * 4 + rr;
        int col = n0 + nt * 16 + lrow;
        xwb[(size_t)(m0 + row) * D_DIM + col] = f2h(acc[mt][nt][rr] + Wb[col]);
      }
}

// ---------------------------------------------------------------------------
// per-edge accumulate: lane s owns cols {2s,2s+1,2s+64,2s+65}.
//   m = gamma[type]*xw[src]+beta[type]  (f16 packed fma, >= bf16-input precision)
//   acc[row][col] += f32(m) via ds_add_f32 no-return atomics (f32 accumulation).
//   All 32 lanes target the same row: 2 lanes/bank = conflict-free.
// NOTE: these DS atomics are inline asm -> INVISIBLE to the waitcnt pass.
//       The caller MUST drain lgkmcnt explicitly before the phase barrier.
// ---------------------------------------------------------------------------
__device__ __forceinline__ void edge_accum(int srcv, int yv, int s,
                                           const unsigned short* __restrict__ xwb,
                                           const unsigned short* __restrict__ gbb,
                                           unsigned int abase) {
  const int tt  = yv & 0xff;
  const int row = yv >> 8;
  const __half2* xr = (const __half2*)(xwb + (size_t)srcv * D_DIM);
  const __half2 x01 = xr[s];
  const __half2 x23 = xr[32 + s];
  uint4v gv = *(const uint4v*)(gbb + tt * 256 + s * 8);
  __half2 m01 = __hfma2(u2h(gv[0]), x01, u2h(gv[1]));
  __half2 m23 = __hfma2(u2h(gv[2]), x23, u2h(gv[3]));
  float2 f01 = __half22float2(m01);
  float2 f23 = __half22float2(m23);
  unsigned int a0 = abase + (unsigned int)((row * LDF + 2 * s) * 4);
  asm volatile("ds_add_f32 %0, %1"            :: "v"(a0), "v"(f01.x));
  asm volatile("ds_add_f32 %0, %1 offset:4"   :: "v"(a0), "v"(f01.y));
  asm volatile("ds_add_f32 %0, %1 offset:256" :: "v"(a0), "v"(f23.x));  // col+64
  asm volatile("ds_add_f32 %0, %1 offset:260" :: "v"(a0), "v"(f23.y));
}

// ---------------------------------------------------------------------------
// Fused gather + node MLP. Block = 32 nodes, 4 waves.
// A0: stage rowptr slice; zero f32 acc tile; stage edges with dst-row packed
//     into y (binary search over rp_lds at staging time).
// A:  edge-parallel gather: 8 half-waves each own a contiguous edge chunk;
//     iterations are independent (unrolled -> many gathers in flight) and
//     accumulate via LDS f32 no-return atomics. Explicit lgkmcnt(0) drain
//     before the barrier (asm DS ops are untracked by the waitcnt pass!).
// R:  residual o = (1+eps)*x + aggr -> bf16 A-tile (separate LDS region).
// B:  t = relu(o @ w0^T + b0) -> t_lds (overlays acc/es region, dead by then).
// C:  y = t @ w1^T + b1 -> global.
// LDS: 20992 (acc f32 + es) + 8704 (A-tile) + 132 (rp) ~= 29.8 KB -> 5 blk/CU.
// ---------------------------------------------------------------------------
__global__ __launch_bounds__(256)
void gather_mlp_kernel(const int2* __restrict__ edges2, const int* __restrict__ rowptr,
                       const float* __restrict__ x, const unsigned short* __restrict__ xwb,
                       const unsigned short* __restrict__ gbb,
                       const float* __restrict__ eps,
                       const unsigned short* __restrict__ w0b, const float* __restrict__ b0,
                       const unsigned short* __restrict__ w1b, const float* __restrict__ b1,
                       float* __restrict__ y) {
  __shared__ __align__(16) unsigned char u_raw[32 * LDF * 4 + ECAP * 8]; // 20992 B
  __shared__ unsigned short ab_lds[32 * LDA];   // 8704 B bf16 A-tile
  __shared__ int rp_lds[33];
  float* accf = (float*)u_raw;                  // [32][LDF] f32, 16896 B
  int2* es = (int2*)(u_raw + 32 * LDF * 4);     // 512 edges, 4096 B
  unsigned short* t_lds = (unsigned short*)u_raw; // [32][LDT] (B/C overlay)

  const int tid = threadIdx.x;
  const int m0 = blockIdx.x * 32;
  const float e1v = 1.0f + eps[0];

  // ---- A0a: rowptr slice + zero acc tile
  if (tid < 33) rp_lds[tid] = rowptr[m0 + tid];
  for (int i = tid; i < 32 * LDF; i += 256) accf[i] = 0.0f;
  __syncthreads();

  const int beg0 = rp_lds[0];
  const int nE = rp_lds[32] - beg0;

  // ---- A0b: stage edges, packing dst-row (5-step binary search) into y
  for (int i = tid; i < nE && i < ECAP; i += 256) {
    int2 ed = edges2[beg0 + i];
    int g = beg0 + i;
    int lo = 0, hi = 32;
    while (hi - lo > 1) { int mid = (lo + hi) >> 1; if (rp_lds[mid] <= g) lo = mid; else hi = mid; }
    es[i] = make_int2(ed.x, ed.y | (lo << 8));
  }
  __syncthreads();

  // ---- A: edge-parallel gather, contiguous chunk per half-wave
  {
    const int h8 = tid >> 5, s = tid & 31;
    const int chunk = (nE + 7) >> 3;
    const int i0 = h8 * chunk;
    const int i1 = (i0 + chunk < nE) ? (i0 + chunk) : nE;
    const unsigned int abase = (unsigned int)(size_t)u_raw;
    if (nE <= ECAP) {
      #pragma unroll 4
      for (int i = i0; i < i1; ++i) {
        int2 ed = es[i];
        edge_accum(ed.x, ed.y, s, xwb, gbb, abase);
      }
    } else {
      for (int i = i0; i < i1; ++i) {
        int srcv, yv;
        if (i < ECAP) { int2 ed = es[i]; srcv = ed.x; yv = ed.y; }
        else {
          int2 ed = edges2[beg0 + i];
          int g = beg0 + i, lo = 0, hi = 32;
          while (hi - lo > 1) { int mid = (lo + hi) >> 1; if (rp_lds[mid] <= g) lo = mid; else hi = mid; }
          srcv = ed.x; yv = ed.y | (lo << 8);
        }
        edge_accum(srcv, yv, s, xwb, gbb, abase);
      }
    }
  }
  // Drain the untracked inline-asm DS atomics BEFORE the barrier: the
  // SIWaitcnts pass cannot see inside asm blobs, so __syncthreads() alone
  // does not guarantee they have committed (this was the R1/R2 failure).
  asm volatile("s_waitcnt lgkmcnt(0)" ::: "memory");
  __syncthreads();

  // ---- R: o = (1+eps)*x + aggr -> bf16 A-tile
  {
    const int row = tid >> 3, c0 = (tid & 7) * 16;
    const float* xr = &x[(size_t)(m0 + row) * D_DIM + c0];
    const float* ar = &accf[row * LDF + c0];
    for (int k = 0; k < 4; ++k) {
      float4 xv = *(const float4*)(xr + 4 * k);
      float4 av = *(const float4*)(ar + 4 * k);
      ushort4v o4;
      o4[0] = f32_to_bf16(e1v * xv.x + av.x);
      o4[1] = f32_to_bf16(e1v * xv.y + av.y);
      o4[2] = f32_to_bf16(e1v * xv.z + av.z);
      o4[3] = f32_to_bf16(e1v * xv.w + av.w);
      *(ushort4v*)&ab_lds[row * LDA + c0 + 4 * k] = o4;
    }
  }
  __syncthreads();

  const int wave = tid >> 6, lane = tid & 63;
  const int lrow = lane & 15, quad = lane >> 4;

  // ---- B: t = relu(o @ w0^T + b0); wave covers cols [wave*64, +64)
  {
    const int n0 = wave * 64;
    f32x4 acc[2][4] = {};
    for (int ks = 0; ks < 128; ks += 32) {
      short8 a0 = *(const short8*)&ab_lds[lrow * LDA + ks + quad * 8];
      short8 a1 = *(const short8*)&ab_lds[(16 + lrow) * LDA + ks + quad * 8];
      for (int nt = 0; nt < 4; ++nt) {
        short8 b = *(const short8*)&w0b[(n0 + nt * 16 + lrow) * D_DIM + ks + quad * 8];
        acc[0][nt] = __builtin_amdgcn_mfma_f32_16x16x32_bf16(a0, b, acc[0][nt], 0, 0, 0);
        acc[1][nt] = __builtin_amdgcn_mfma_f32_16x16x32_bf16(a1, b, acc[1][nt], 0, 0, 0);
      }
    }
    // t_lds overlays accf/es (dead since last barrier); ab_lds reads are safe.
    for (int mt = 0; mt < 2; ++mt)
      for (int nt = 0; nt < 4; ++nt)
        for (int rr = 0; rr < 4; ++rr) {
          int row = mt * 16 + quad * 4 + rr;
          int col = n0 + nt * 16 + lrow;
          float v = acc[mt][nt][rr] + b0[col];
          t_lds[row * LDT + col] = f32_to_bf16(fmaxf(v, 0.0f));
        }
  }
  __syncthreads();

  // ---- C: y = t @ w1^T + b1; wave covers cols [wave*32, +32)
  {
    const int n0 = wave * 32;
    f32x4 acc[2][2] = {};
    for (int ks = 0; ks < 256; ks += 32) {
      short8 a0 = *(const short8*)&t_lds[lrow * LDT + ks + quad * 8];
      short8 a1 = *(const short8*)&t_lds[(16 + lrow) * LDT + ks + quad * 8];
      for (int nt = 0; nt < 2; ++nt) {
        short8 b = *(const short8*)&w1b[(n0 + nt * 16 + lrow) * 2 * D_DIM + ks + quad * 8];
        acc[0][nt] = __builtin_amdgcn_mfma_f32_16x16x32_bf16(a0, b, acc[0][nt], 0, 0, 0);
        acc[1][nt] = __builtin_amdgcn_mfma_f32_16x16x32_bf16(a1, b, acc[1][nt], 0, 0, 0);
      }
    }
    for (int mt = 0; mt < 2; ++mt)
      for (int nt = 0; nt < 2; ++nt)
        for (int rr = 0; rr < 4; ++rr) {
          int row = mt * 16 + quad * 4 + rr;
          int col = n0 + nt * 16 + lrow;
          y[(size_t)(m0 + row) * D_DIM + col] = acc[mt][nt][rr] + b1[col];
        }
  }
}

// ---------------------------------------------------------------------------
extern "C" void kernel_launch(void* const* d_in, const int* in_sizes, int n_in,
                              void* d_out, int out_size, void* d_ws, size_t ws_size,
                              hipStream_t stream) {
  const int*   ei      = (const int*)d_in[0];
  const int*   et      = (const int*)d_in[1];
  const float* embed   = (const float*)d_in[2];
  const float* rel_emb = (const float*)d_in[3];
  const float* rmw0 = (const float*)d_in[4];  const float* rmb0 = (const float*)d_in[5];
  const float* rmw1 = (const float*)d_in[6];  const float* rmb1 = (const float*)d_in[7];
  const float* rmw2 = (const float*)d_in[8];  const float* rmb2 = (const float*)d_in[9];
  const float* rmw3 = (const float*)d_in[10]; const float* rmb3 = (const float*)d_in[11];
  const float* Ww   = (const float*)d_in[12]; const float* Wb   = (const float*)d_in[13];
  const float* mw0  = (const float*)d_in[14]; const float* mb0  = (const float*)d_in[15];
  const float* mw1  = (const float*)d_in[16]; const float* mb1  = (const float*)d_in[17];
  const float* eps  = (const float*)d_in[18];
  float* out = (float*)d_out;

  // workspace layout
  float*          W1   = (float*)d_ws;                          // N*D f32
  unsigned short* xwb  = (unsigned short*)(W1 + (size_t)N_NODES * D_DIM);  // N*D f16
  unsigned short* gbb  = xwb + (size_t)N_NODES * D_DIM;         // L*R*256 f16
  unsigned short* Wwb  = gbb + L_LAYERS * R_REL * 256;          // L*128*128 bf16
  unsigned short* mw0b = Wwb + L_LAYERS * D_DIM * D_DIM;        // L*256*128 bf16
  unsigned short* mw1b = mw0b + L_LAYERS * 2 * D_DIM * D_DIM;   // L*128*256 bf16
  int*   deg     = (int*)(mw1b + L_LAYERS * 2 * D_DIM * D_DIM); // N
  int*   rowptr  = deg + N_NODES;                               // N+1
  int*   cursor  = rowptr + N_NODES + 1;                        // N
  int*   partial = cursor + N_NODES;                            // NBLK_SCAN
  int*   blockoff= partial + NBLK_SCAN;                         // NBLK_SCAN
  int2*  edges2  = (int2*)(blockoff + NBLK_SCAN + 1);           // E int2

  // ---- one-shot preprocessing
  hipMemsetAsync(deg, 0, N_NODES * sizeof(int), stream);
  hist_kernel<<<N_EDGES / 256, 256, 0, stream>>>(ei, deg);
  scan_part1<<<NBLK_SCAN, 256, 0, stream>>>(deg, partial);
  scan_part2<<<1, 128, 0, stream>>>(partial, blockoff);
  scan_part3<<<NBLK_SCAN, 256, 0, stream>>>(deg, blockoff, rowptr, cursor);
  scatter_kernel<<<N_EDGES / 256, 256, 0, stream>>>(ei, et, cursor, edges2);
  prep_kernel<<<384, 256, 0, stream>>>(rel_emb, rmw0, rmb0, rmw1, rmb1,
                                       rmw2, rmb2, rmw3, rmb3, gbb,
                                       Ww, mw0, mw1, Wwb, mw0b, mw1b);

  const int gN = N_NODES / 32;        // 3125

  // ---- layer 0: x = embed -> xwb -> fused gather+mlp -> W1
  xw_kernel<<<gN, 256, 0, stream>>>(embed, Wwb, Wb, xwb);
  gather_mlp_kernel<<<gN, 256, 0, stream>>>(edges2, rowptr, embed, xwb, gbb, eps,
                                            mw0b, mb0, mw1b, mb1, W1);

  // ---- layer 1: x = W1 -> xwb -> fused gather+mlp -> d_out
  xw_kernel<<<gN, 256, 0, stream>>>(W1, Wwb + D_DIM * D_DIM, Wb + D_DIM, xwb);
  gather_mlp_kernel<<<gN, 256, 0, stream>>>(edges2, rowptr, W1, xwb,
                                            gbb + R_REL * 256, eps + 1,
                                            mw0b + 2 * D_DIM * D_DIM, mb0 + 2 * D_DIM,
                                            mw1b + 2 * D_DIM * D_DIM, mb1 + D_DIM, out);
}

// Round 4
// 467.640 us; speedup vs baseline: 2.5243x; 2.5243x over previous
//
#include <hip/hip_runtime.h>
#include <hip/hip_fp16.h>
#include <stdint.h>

#define N_NODES 100000
#define N_EDGES 640000
#define R_REL   64
#define D_DIM   128
#define L_LAYERS 2

#define SCAN_CHUNK 1024
#define NBLK_SCAN ((N_NODES + SCAN_CHUNK - 1) / SCAN_CHUNK)   // 98

#define LDA 136   // bf16 tile stride (128 + 8 pad)
#define LDT 264   // bf16 t-tile stride (256 + 8 pad)

typedef __attribute__((ext_vector_type(8))) short   short8;   // 8 bf16 MFMA frag
typedef __attribute__((ext_vector_type(4))) unsigned short ushort4v;
typedef __attribute__((ext_vector_type(4))) float   f32x4;

__device__ __forceinline__ unsigned short f32_to_bf16(float f) {
  union { float f; uint32_t u; } v; v.f = f;
  uint32_t u = v.u;
  u += 0x7fffu + ((u >> 16) & 1u);   // RNE (finite inputs only)
  return (unsigned short)(u >> 16);
}
__device__ __forceinline__ unsigned short f2h(float f) {
  __half h = __float2half(f);
  return __half_as_ushort(h);
}
__device__ __forceinline__ __half2 u2h(unsigned int u) {
  union { unsigned int u; __half2 h; } v; v.u = u; return v.h;
}

// ---------------------------------------------------------------------------
// CSR build: histogram -> 3-kernel exclusive scan -> slot scatter
// ---------------------------------------------------------------------------
__global__ __launch_bounds__(256)
void hist_kernel(const int* __restrict__ ei, int* __restrict__ deg) {
  int idx = blockIdx.x * 256 + threadIdx.x;
  atomicAdd(&deg[ei[N_EDGES + idx]], 1);
}

__global__ __launch_bounds__(256)
void scan_part1(const int* __restrict__ deg, int* __restrict__ partial) {
  __shared__ int lds[256];
  const int b = blockIdx.x, t = threadIdx.x;
  const int base = b * SCAN_CHUNK + t * 4;
  int s = 0;
  for (int k = 0; k < 4; ++k) { int i = base + k; s += (i < N_NODES) ? deg[i] : 0; }
  lds[t] = s; __syncthreads();
  for (int off = 128; off > 0; off >>= 1) {
    if (t < off) lds[t] += lds[t + off];
    __syncthreads();
  }
  if (t == 0) partial[b] = lds[0];
}

__global__ __launch_bounds__(128)
void scan_part2(int* __restrict__ partial, int* __restrict__ blockoff) {
  __shared__ int lds[128];
  const int t = threadIdx.x;
  const int v = (t < NBLK_SCAN) ? partial[t] : 0;
  lds[t] = v; __syncthreads();
  for (int off = 1; off < 128; off <<= 1) {
    int add = (t >= off) ? lds[t - off] : 0;
    __syncthreads();
    lds[t] += add;
    __syncthreads();
  }
  if (t < NBLK_SCAN) blockoff[t] = lds[t] - v;   // exclusive
}

__global__ __launch_bounds__(256)
void scan_part3(const int* __restrict__ deg, const int* __restrict__ blockoff,
                int* __restrict__ rowptr, int* __restrict__ cursor) {
  __shared__ int lds[256];
  const int b = blockIdx.x, t = threadIdx.x;
  const int base = b * SCAN_CHUNK + t * 4;
  int v[4]; int s = 0;
  for (int k = 0; k < 4; ++k) {
    int i = base + k;
    v[k] = (i < N_NODES) ? deg[i] : 0;
    s += v[k];
  }
  lds[t] = s; __syncthreads();
  for (int off = 1; off < 256; off <<= 1) {
    int add = (t >= off) ? lds[t - off] : 0;
    __syncthreads();
    lds[t] += add;
    __syncthreads();
  }
  int excl = lds[t] - s + blockoff[b];
  for (int k = 0; k < 4; ++k) {
    int i = base + k;
    if (i < N_NODES) { rowptr[i] = excl; cursor[i] = excl; excl += v[k]; }
  }
  if (b == 0 && t == 0) rowptr[N_NODES] = N_EDGES;
}

__global__ __launch_bounds__(256)
void scatter_kernel(const int* __restrict__ ei, const int* __restrict__ et,
                    int* __restrict__ cursor, int2* __restrict__ edges2) {
  int idx = blockIdx.x * 256 + threadIdx.x;
  int dst = ei[N_EDGES + idx];
  int slot = atomicAdd(&cursor[dst], 1);
  edges2[slot] = make_int2(ei[idx], et[idx]);
}

// ---------------------------------------------------------------------------
// prep: blocks [0,128): gamma/beta -> packed f16 gbb.
//       blocks [128,384): weight f32->bf16 conversion (MFMA weights).
// gbb layout per type t (256 f16): lane l (0..63) holds 4 halfs at t*256+l*4:
//   { g[2l], g[2l+1], b[2l], b[2l+1] }
// so one 8B load per edge covers lane l's 2 columns {2l, 2l+1}.
// ---------------------------------------------------------------------------
__global__ __launch_bounds__(256)
void prep_kernel(const float* __restrict__ rel_emb,
                 const float* __restrict__ rmw0, const float* __restrict__ rmb0,
                 const float* __restrict__ rmw1, const float* __restrict__ rmb1,
                 const float* __restrict__ rmw2, const float* __restrict__ rmb2,
                 const float* __restrict__ rmw3, const float* __restrict__ rmb3,
                 unsigned short* __restrict__ gbb,
                 const float* __restrict__ Ww, const float* __restrict__ mw0,
                 const float* __restrict__ mw1,
                 unsigned short* __restrict__ Wwb, unsigned short* __restrict__ mw0b,
                 unsigned short* __restrict__ mw1b) {
  if (blockIdx.x >= 128) {
    int i = (blockIdx.x - 128) * 256 + threadIdx.x;   // 0..65535
    if (i < L_LAYERS * D_DIM * D_DIM)     Wwb[i]  = f32_to_bf16(Ww[i]);
    if (i < L_LAYERS * 2 * D_DIM * D_DIM) mw0b[i] = f32_to_bf16(mw0[i]);
    if (i < L_LAYERS * 2 * D_DIM * D_DIM) mw1b[i] = f32_to_bf16(mw1[i]);
    return;
  }
  __shared__ float bufA[2 * D_DIM];
  __shared__ float bufB[2 * D_DIM];
  const int l = blockIdx.x >> 6;
  const int r = blockIdx.x & 63;
  const int j = threadIdx.x;   // 0..255

  if (j < D_DIM) bufA[j] = rel_emb[(l * R_REL + r) * D_DIM + j];
  __syncthreads();
  {
    const float* w = rmw0 + ((size_t)l * 2 * D_DIM + j) * D_DIM;
    float s = rmb0[l * 2 * D_DIM + j];
    for (int k = 0; k < D_DIM; k += 4) {
      float4 wv = *(const float4*)(w + k);
      s += wv.x * bufA[k] + wv.y * bufA[k + 1] + wv.z * bufA[k + 2] + wv.w * bufA[k + 3];
    }
    bufB[j] = fmaxf(s, 0.0f);
  }
  __syncthreads();
  {
    const float* w = rmw1 + ((size_t)l * 2 * D_DIM + j) * 2 * D_DIM;
    float s = rmb1[l * 2 * D_DIM + j];
    for (int k = 0; k < 2 * D_DIM; k += 4) {
      float4 wv = *(const float4*)(w + k);
      s += wv.x * bufB[k] + wv.y * bufB[k + 1] + wv.z * bufB[k + 2] + wv.w * bufB[k + 3];
    }
    __syncthreads();
    bufA[j] = fmaxf(s, 0.0f);
  }
  __syncthreads();
  {
    const float* w = rmw2 + ((size_t)l * 2 * D_DIM + j) * 2 * D_DIM;
    float s = rmb2[l * 2 * D_DIM + j];
    for (int k = 0; k < 2 * D_DIM; k += 4) {
      float4 wv = *(const float4*)(w + k);
      s += wv.x * bufA[k] + wv.y * bufA[k + 1] + wv.z * bufA[k + 2] + wv.w * bufA[k + 3];
    }
    __syncthreads();
    bufB[j] = fmaxf(s, 0.0f);
  }
  __syncthreads();
  {
    const float* w = rmw3 + ((size_t)l * 2 * D_DIM + j) * 2 * D_DIM;
    float s = rmb3[l * 2 * D_DIM + j];
    for (int k = 0; k < 2 * D_DIM; k += 4) {
      float4 wv = *(const float4*)(w + k);
      s += wv.x * bufB[k] + wv.y * bufB[k + 1] + wv.z * bufB[k + 2] + wv.w * bufB[k + 3];
    }
    const int t = l * R_REL + r;
    if (j < D_DIM) {            // gamma col j -> slot (j>>1)*4 + (j&1)
      gbb[t * 256 + (j >> 1) * 4 + (j & 1)] = f2h(s);
    } else {                    // beta col c -> slot (c>>1)*4 + 2 + (c&1)
      int c = j - D_DIM;
      gbb[t * 256 + (c >> 1) * 4 + 2 + (c & 1)] = f2h(s);
    }
  }
}

// ---------------------------------------------------------------------------
// xw = f16( x @ Ww^T + Wb )  (N x 128). bf16 MFMA weights, f16 output.
// (used for layer 0 only; layer 1's xw is fused into mlp_kernel phase D)
// ---------------------------------------------------------------------------
__global__ __launch_bounds__(256)
void xw_kernel(const float* __restrict__ x,
               const unsigned short* __restrict__ Wwb,  // 128x128 bf16 layer slice
               const float* __restrict__ Wb,            // 128
               unsigned short* __restrict__ xwb) {      // f16 bits out
  __shared__ unsigned short a_lds[32 * LDA];
  const int tid = threadIdx.x;
  const int m0 = blockIdx.x * 32;

  for (int i = tid; i < 1024; i += 256) {
    int row = i >> 5, ch = i & 31;
    float4 v = *(const float4*)&x[(m0 + row) * D_DIM + ch * 4];
    ushort4v s;
    s[0] = f32_to_bf16(v.x); s[1] = f32_to_bf16(v.y);
    s[2] = f32_to_bf16(v.z); s[3] = f32_to_bf16(v.w);
    *(ushort4v*)&a_lds[row * LDA + ch * 4] = s;
  }
  __syncthreads();

  const int wave = tid >> 6, lane = tid & 63;
  const int lrow = lane & 15, quad = lane >> 4;
  const int n0 = wave * 32;

  f32x4 acc[2][2] = {};
  for (int ks = 0; ks < 128; ks += 32) {
    short8 a0 = *(const short8*)&a_lds[lrow * LDA + ks + quad * 8];
    short8 a1 = *(const short8*)&a_lds[(16 + lrow) * LDA + ks + quad * 8];
    short8 b0 = *(const short8*)&Wwb[(n0 + lrow) * D_DIM + ks + quad * 8];
    short8 b1 = *(const short8*)&Wwb[(n0 + 16 + lrow) * D_DIM + ks + quad * 8];
    acc[0][0] = __builtin_amdgcn_mfma_f32_16x16x32_bf16(a0, b0, acc[0][0], 0, 0, 0);
    acc[0][1] = __builtin_amdgcn_mfma_f32_16x16x32_bf16(a0, b1, acc[0][1], 0, 0, 0);
    acc[1][0] = __builtin_amdgcn_mfma_f32_16x16x32_bf16(a1, b0, acc[1][0], 0, 0, 0);
    acc[1][1] = __builtin_amdgcn_mfma_f32_16x16x32_bf16(a1, b1, acc[1][1], 0, 0, 0);
  }

  for (int mt = 0; mt < 2; ++mt)
    for (int nt = 0; nt < 2; ++nt)
      for (int rr = 0; rr < 4; ++rr) {
        int row = mt * 16 + quad * 4 + rr;
        int col = n0 + nt * 16 + lrow;
        xwb[(size_t)(m0 + row) * D_DIM + col] = f2h(acc[mt][nt][rr] + Wb[col]);
      }
}

// ---------------------------------------------------------------------------
// agg: one WAVE per node. Lane l owns cols {2l, 2l+1}; the wave walks the
// node's CSR edge slice (edge index wave-uniform -> scalar loads); per-edge
// m = gamma*xw[src]+beta via one __hfma2, accumulated in 2 f32 REGISTERS.
// No atomics, no shuffles. 2-edge unroll breaks the load->use chain.
// o = bf16((1+eps)*x + aggr) written coalesced (4B/lane).
// ---------------------------------------------------------------------------
__global__ __launch_bounds__(256)
void agg_kernel(const int2* __restrict__ edges2, const int* __restrict__ rowptr,
                const float* __restrict__ x, const unsigned short* __restrict__ xwb,
                const unsigned short* __restrict__ gbt, const float* __restrict__ eps,
                unsigned short* __restrict__ o) {
  const int lane = threadIdx.x & 63;
  const int n = __builtin_amdgcn_readfirstlane(blockIdx.x * 4 + (threadIdx.x >> 6));
  const int beg = rowptr[n], end = rowptr[n + 1];

  float acc0 = 0.0f, acc1 = 0.0f;
  int e = beg;
  for (; e + 2 <= end; e += 2) {
    int2 ed0 = edges2[e];
    int2 ed1 = edges2[e + 1];
    __half2 xa = *(const __half2*)&xwb[(size_t)ed0.x * D_DIM + lane * 2];
    __half2 xb = *(const __half2*)&xwb[(size_t)ed1.x * D_DIM + lane * 2];
    uint2 ga = *(const uint2*)&gbt[ed0.y * 256 + lane * 4];   // {g01, b01}
    uint2 gb = *(const uint2*)&gbt[ed1.y * 256 + lane * 4];
    __half2 m0 = __hfma2(u2h(ga.x), xa, u2h(ga.y));
    __half2 m1 = __hfma2(u2h(gb.x), xb, u2h(gb.y));
    float2 f0 = __half22float2(m0);
    float2 f1 = __half22float2(m1);
    acc0 += f0.x + f1.x;
    acc1 += f0.y + f1.y;
  }
  if (e < end) {
    int2 ed0 = edges2[e];
    __half2 xa = *(const __half2*)&xwb[(size_t)ed0.x * D_DIM + lane * 2];
    uint2 ga = *(const uint2*)&gbt[ed0.y * 256 + lane * 4];
    __half2 m0 = __hfma2(u2h(ga.x), xa, u2h(ga.y));
    float2 f0 = __half22float2(m0);
    acc0 += f0.x;
    acc1 += f0.y;
  }

  const float e1v = 1.0f + eps[0];
  float2 xr = *(const float2*)&x[(size_t)n * D_DIM + lane * 2];
  unsigned int w = (unsigned int)f32_to_bf16(e1v * xr.x + acc0)
                 | ((unsigned int)f32_to_bf16(e1v * xr.y + acc1) << 16);
  *(unsigned int*)&o[(size_t)n * D_DIM + lane * 2] = w;
}

// ---------------------------------------------------------------------------
// mlp: block = 32 nodes, 4 waves.
// stage: o tile (bf16) -> a_lds.
// B: t = relu(o @ w0^T + b0) -> t_lds.
// C: y = t @ w1^T + b1 -> global f32; if fusing, also y bf16 -> a_lds overlay.
// D (optional): xwbN = f16(y @ WwN^T + WbN)  — next layer's xw, fused.
// LDS: 8704 (a/y) + 16896 (t) = 25.6 KB -> 6 blocks/CU.
// ---------------------------------------------------------------------------
__global__ __launch_bounds__(256)
void mlp_kernel(const unsigned short* __restrict__ o,
                const unsigned short* __restrict__ w0b, const float* __restrict__ b0,
                const unsigned short* __restrict__ w1b, const float* __restrict__ b1,
                float* __restrict__ y,
                const unsigned short* __restrict__ WwNb,  // next-layer Ww bf16 (or null)
                const float* __restrict__ WbN,            // next-layer bias
                unsigned short* __restrict__ xwbN) {      // next-layer xw f16 out
  __shared__ unsigned short a_lds[32 * LDA];   // o tile; later y tile (phase D)
  __shared__ unsigned short t_lds[32 * LDT];
  const int tid = threadIdx.x;
  const int m0 = blockIdx.x * 32;

  // ---- stage o tile (bf16, coalesced 16B loads)
  for (int i = tid; i < 512; i += 256) {
    int row = i >> 4, seg = i & 15;
    *(short8*)&a_lds[row * LDA + seg * 8] =
        *(const short8*)&o[(size_t)(m0 + row) * D_DIM + seg * 8];
  }
  __syncthreads();

  const int wave = tid >> 6, lane = tid & 63;
  const int lrow = lane & 15, quad = lane >> 4;

  // ---- B: t = relu(o @ w0^T + b0); wave covers cols [wave*64, +64)
  {
    const int n0 = wave * 64;
    f32x4 acc[2][4] = {};
    for (int ks = 0; ks < 128; ks += 32) {
      short8 a0 = *(const short8*)&a_lds[lrow * LDA + ks + quad * 8];
      short8 a1 = *(const short8*)&a_lds[(16 + lrow) * LDA + ks + quad * 8];
      for (int nt = 0; nt < 4; ++nt) {
        short8 b = *(const short8*)&w0b[(n0 + nt * 16 + lrow) * D_DIM + ks + quad * 8];
        acc[0][nt] = __builtin_amdgcn_mfma_f32_16x16x32_bf16(a0, b, acc[0][nt], 0, 0, 0);
        acc[1][nt] = __builtin_amdgcn_mfma_f32_16x16x32_bf16(a1, b, acc[1][nt], 0, 0, 0);
      }
    }
    __syncthreads();   // all waves done reading a_lds (and t region untouched yet)
    for (int mt = 0; mt < 2; ++mt)
      for (int nt = 0; nt < 4; ++nt)
        for (int rr = 0; rr < 4; ++rr) {
          int row = mt * 16 + quad * 4 + rr;
          int col = n0 + nt * 16 + lrow;
          float v = acc[mt][nt][rr] + b0[col];
          t_lds[row * LDT + col] = f32_to_bf16(fmaxf(v, 0.0f));
        }
  }
  __syncthreads();

  // ---- C: y = t @ w1^T + b1; wave covers cols [wave*32, +32)
  {
    const int n0 = wave * 32;
    f32x4 acc[2][2] = {};
    for (int ks = 0; ks < 256; ks += 32) {
      short8 a0 = *(const short8*)&t_lds[lrow * LDT + ks + quad * 8];
      short8 a1 = *(const short8*)&t_lds[(16 + lrow) * LDT + ks + quad * 8];
      for (int nt = 0; nt < 2; ++nt) {
        short8 b = *(const short8*)&w1b[(n0 + nt * 16 + lrow) * 2 * D_DIM + ks + quad * 8];
        acc[0][nt] = __builtin_amdgcn_mfma_f32_16x16x32_bf16(a0, b, acc[0][nt], 0, 0, 0);
        acc[1][nt] = __builtin_amdgcn_mfma_f32_16x16x32_bf16(a1, b, acc[1][nt], 0, 0, 0);
      }
    }
    for (int mt = 0; mt < 2; ++mt)
      for (int nt = 0; nt < 2; ++nt)
        for (int rr = 0; rr < 4; ++rr) {
          int row = mt * 16 + quad * 4 + rr;
          int col = n0 + nt * 16 + lrow;
          float v = acc[mt][nt][rr] + b1[col];
          y[(size_t)(m0 + row) * D_DIM + col] = v;
          if (xwbN) a_lds[row * LDA + col] = f32_to_bf16(v);   // y tile for D
        }
  }

  // ---- D (fused next-layer xw): xwbN = f16(y @ WwN^T + WbN)
  if (xwbN) {
    __syncthreads();   // y tile complete in a_lds
    const int n0 = wave * 32;
    f32x4 acc[2][2] = {};
    for (int ks = 0; ks < 128; ks += 32) {
      short8 a0 = *(const short8*)&a_lds[lrow * LDA + ks + quad * 8];
      short8 a1 = *(const short8*)&a_lds[(16 + lrow) * LDA + ks + quad * 8];
      short8 b0 = *(const short8*)&WwNb[(n0 + lrow) * D_DIM + ks + quad * 8];
      short8 b1 = *(const short8*)&WwNb[(n0 + 16 + lrow) * D_DIM + ks + quad * 8];
      acc[0][0] = __builtin_amdgcn_mfma_f32_16x16x32_bf16(a0, b0, acc[0][0], 0, 0, 0);
      acc[0][1] = __builtin_amdgcn_mfma_f32_16x16x32_bf16(a0, b1, acc[0][1], 0, 0, 0);
      acc[1][0] = __builtin_amdgcn_mfma_f32_16x16x32_bf16(a1, b0, acc[1][0], 0, 0, 0);
      acc[1][1] = __builtin_amdgcn_mfma_f32_16x16x32_bf16(a1, b1, acc[1][1], 0, 0, 0);
    }
    for (int mt = 0; mt < 2; ++mt)
      for (int nt = 0; nt < 2; ++nt)
        for (int rr = 0; rr < 4; ++rr) {
          int row = mt * 16 + quad * 4 + rr;
          int col = n0 + nt * 16 + lrow;
          xwbN[(size_t)(m0 + row) * D_DIM + col] = f2h(acc[mt][nt][rr] + WbN[col]);
        }
  }
}

// ---------------------------------------------------------------------------
extern "C" void kernel_launch(void* const* d_in, const int* in_sizes, int n_in,
                              void* d_out, int out_size, void* d_ws, size_t ws_size,
                              hipStream_t stream) {
  const int*   ei      = (const int*)d_in[0];
  const int*   et      = (const int*)d_in[1];
  const float* embed   = (const float*)d_in[2];
  const float* rel_emb = (const float*)d_in[3];
  const float* rmw0 = (const float*)d_in[4];  const float* rmb0 = (const float*)d_in[5];
  const float* rmw1 = (const float*)d_in[6];  const float* rmb1 = (const float*)d_in[7];
  const float* rmw2 = (const float*)d_in[8];  const float* rmb2 = (const float*)d_in[9];
  const float* rmw3 = (const float*)d_in[10]; const float* rmb3 = (const float*)d_in[11];
  const float* Ww   = (const float*)d_in[12]; const float* Wb   = (const float*)d_in[13];
  const float* mw0  = (const float*)d_in[14]; const float* mb0  = (const float*)d_in[15];
  const float* mw1  = (const float*)d_in[16]; const float* mb1  = (const float*)d_in[17];
  const float* eps  = (const float*)d_in[18];
  float* out = (float*)d_out;

  // workspace layout
  float*          W1   = (float*)d_ws;                          // N*D f32
  unsigned short* xwb  = (unsigned short*)(W1 + (size_t)N_NODES * D_DIM);  // N*D f16
  unsigned short* gbb  = xwb + (size_t)N_NODES * D_DIM;         // L*R*256 f16
  unsigned short* Wwb  = gbb + L_LAYERS * R_REL * 256;          // L*128*128 bf16
  unsigned short* mw0b = Wwb + L_LAYERS * D_DIM * D_DIM;        // L*256*128 bf16
  unsigned short* mw1b = mw0b + L_LAYERS * 2 * D_DIM * D_DIM;   // L*128*256 bf16
  int*   deg     = (int*)(mw1b + L_LAYERS * 2 * D_DIM * D_DIM); // N
  int*   rowptr  = deg + N_NODES;                               // N+1
  int*   cursor  = rowptr + N_NODES + 1;                        // N
  int*   partial = cursor + N_NODES;                            // NBLK_SCAN
  int*   blockoff= partial + NBLK_SCAN;                         // NBLK_SCAN
  int2*  edges2  = (int2*)(blockoff + NBLK_SCAN + 1);           // E int2
  unsigned short* obuf = (unsigned short*)(edges2 + N_EDGES);   // N*D bf16

  // ---- one-shot preprocessing
  hipMemsetAsync(deg, 0, N_NODES * sizeof(int), stream);
  hist_kernel<<<N_EDGES / 256, 256, 0, stream>>>(ei, deg);
  scan_part1<<<NBLK_SCAN, 256, 0, stream>>>(deg, partial);
  scan_part2<<<1, 128, 0, stream>>>(partial, blockoff);
  scan_part3<<<NBLK_SCAN, 256, 0, stream>>>(deg, blockoff, rowptr, cursor);
  scatter_kernel<<<N_EDGES / 256, 256, 0, stream>>>(ei, et, cursor, edges2);
  prep_kernel<<<384, 256, 0, stream>>>(rel_emb, rmw0, rmb0, rmw1, rmb1,
                                       rmw2, rmb2, rmw3, rmb3, gbb,
                                       Ww, mw0, mw1, Wwb, mw0b, mw1b);

  const int gN = N_NODES / 32;        // 3125
  const int gA = N_NODES / 4;         // 25000 (wave per node)

  // ---- layer 0
  xw_kernel<<<gN, 256, 0, stream>>>(embed, Wwb, Wb, xwb);
  agg_kernel<<<gA, 256, 0, stream>>>(edges2, rowptr, embed, xwb, gbb, eps, obuf);
  mlp_kernel<<<gN, 256, 0, stream>>>(obuf, mw0b, mb0, mw1b, mb1, W1,
                                     Wwb + D_DIM * D_DIM, Wb + D_DIM, xwb);  // fused xw(L1)

  // ---- layer 1
  agg_kernel<<<gA, 256, 0, stream>>>(edges2, rowptr, W1, xwb,
                                     gbb + R_REL * 256, eps + 1, obuf);
  mlp_kernel<<<gN, 256, 0, stream>>>(obuf, mw0b + 2 * D_DIM * D_DIM, mb0 + 2 * D_DIM,
                                     mw1b + 2 * D_DIM * D_DIM, mb1 + D_DIM, out,
                                     nullptr, nullptr, nullptr);
}

// Round 5
// 436.619 us; speedup vs baseline: 2.7036x; 1.0710x over previous
//
#include <hip/hip_runtime.h>
#include <hip/hip_fp16.h>
#include <stdint.h>

#define N_NODES 100000
#define N_EDGES 640000
#define R_REL   64
#define D_DIM   128
#define L_LAYERS 2

#define SCAN_CHUNK 1024
#define NBLK_SCAN ((N_NODES + SCAN_CHUNK - 1) / SCAN_CHUNK)   // 98

#define LDA 136   // bf16 tile stride (128 + 8 pad)
#define LDT 264   // bf16 t-tile stride (256 + 8 pad)
#define MROWS 128 // mlp tile rows
#define GMLP ((N_NODES + MROWS - 1) / MROWS)   // 782

typedef __attribute__((ext_vector_type(8))) short   short8;   // 8 bf16 MFMA frag
typedef __attribute__((ext_vector_type(4))) unsigned short ushort4v;
typedef __attribute__((ext_vector_type(4))) float   f32x4;

__device__ __forceinline__ unsigned short f32_to_bf16(float f) {
  union { float f; uint32_t u; } v; v.f = f;
  uint32_t u = v.u;
  u += 0x7fffu + ((u >> 16) & 1u);   // RNE (finite inputs only)
  return (unsigned short)(u >> 16);
}
__device__ __forceinline__ unsigned short f2h(float f) {
  __half h = __float2half(f);
  return __half_as_ushort(h);
}
__device__ __forceinline__ __half2 u2h(unsigned int u) {
  union { unsigned int u; __half2 h; } v; v.u = u; return v.h;
}

// ---------------------------------------------------------------------------
// CSR build: histogram -> 3-kernel exclusive scan -> slot scatter
// ---------------------------------------------------------------------------
__global__ __launch_bounds__(256)
void hist_kernel(const int* __restrict__ ei, int* __restrict__ deg) {
  int idx = blockIdx.x * 256 + threadIdx.x;
  atomicAdd(&deg[ei[N_EDGES + idx]], 1);
}

__global__ __launch_bounds__(256)
void scan_part1(const int* __restrict__ deg, int* __restrict__ partial) {
  __shared__ int lds[256];
  const int b = blockIdx.x, t = threadIdx.x;
  const int base = b * SCAN_CHUNK + t * 4;
  int s = 0;
  for (int k = 0; k < 4; ++k) { int i = base + k; s += (i < N_NODES) ? deg[i] : 0; }
  lds[t] = s; __syncthreads();
  for (int off = 128; off > 0; off >>= 1) {
    if (t < off) lds[t] += lds[t + off];
    __syncthreads();
  }
  if (t == 0) partial[b] = lds[0];
}

__global__ __launch_bounds__(128)
void scan_part2(int* __restrict__ partial, int* __restrict__ blockoff) {
  __shared__ int lds[128];
  const int t = threadIdx.x;
  const int v = (t < NBLK_SCAN) ? partial[t] : 0;
  lds[t] = v; __syncthreads();
  for (int off = 1; off < 128; off <<= 1) {
    int add = (t >= off) ? lds[t - off] : 0;
    __syncthreads();
    lds[t] += add;
    __syncthreads();
  }
  if (t < NBLK_SCAN) blockoff[t] = lds[t] - v;   // exclusive
}

__global__ __launch_bounds__(256)
void scan_part3(const int* __restrict__ deg, const int* __restrict__ blockoff,
                int* __restrict__ rowptr, int* __restrict__ cursor) {
  __shared__ int lds[256];
  const int b = blockIdx.x, t = threadIdx.x;
  const int base = b * SCAN_CHUNK + t * 4;
  int v[4]; int s = 0;
  for (int k = 0; k < 4; ++k) {
    int i = base + k;
    v[k] = (i < N_NODES) ? deg[i] : 0;
    s += v[k];
  }
  lds[t] = s; __syncthreads();
  for (int off = 1; off < 256; off <<= 1) {
    int add = (t >= off) ? lds[t - off] : 0;
    __syncthreads();
    lds[t] += add;
    __syncthreads();
  }
  int excl = lds[t] - s + blockoff[b];
  for (int k = 0; k < 4; ++k) {
    int i = base + k;
    if (i < N_NODES) { rowptr[i] = excl; cursor[i] = excl; excl += v[k]; }
  }
  if (b == 0 && t == 0) rowptr[N_NODES] = N_EDGES;
}

__global__ __launch_bounds__(256)
void scatter_kernel(const int* __restrict__ ei, const int* __restrict__ et,
                    int* __restrict__ cursor, int2* __restrict__ edges2) {
  int idx = blockIdx.x * 256 + threadIdx.x;
  int dst = ei[N_EDGES + idx];
  int slot = atomicAdd(&cursor[dst], 1);
  edges2[slot] = make_int2(ei[idx], et[idx]);
}

// ---------------------------------------------------------------------------
// prep: blocks [0,128): gamma/beta -> packed f16 gbb.
//       blocks [128,384): weight f32->bf16 conversion (MFMA weights).
// gbb layout per type t (256 f16): lane l (0..63) holds 4 halfs at t*256+l*4:
//   { g[2l], g[2l+1], b[2l], b[2l+1] }
// ---------------------------------------------------------------------------
__global__ __launch_bounds__(256)
void prep_kernel(const float* __restrict__ rel_emb,
                 const float* __restrict__ rmw0, const float* __restrict__ rmb0,
                 const float* __restrict__ rmw1, const float* __restrict__ rmb1,
                 const float* __restrict__ rmw2, const float* __restrict__ rmb2,
                 const float* __restrict__ rmw3, const float* __restrict__ rmb3,
                 unsigned short* __restrict__ gbb,
                 const float* __restrict__ Ww, const float* __restrict__ mw0,
                 const float* __restrict__ mw1,
                 unsigned short* __restrict__ Wwb, unsigned short* __restrict__ mw0b,
                 unsigned short* __restrict__ mw1b) {
  if (blockIdx.x >= 128) {
    int i = (blockIdx.x - 128) * 256 + threadIdx.x;   // 0..65535
    if (i < L_LAYERS * D_DIM * D_DIM)     Wwb[i]  = f32_to_bf16(Ww[i]);
    if (i < L_LAYERS * 2 * D_DIM * D_DIM) mw0b[i] = f32_to_bf16(mw0[i]);
    if (i < L_LAYERS * 2 * D_DIM * D_DIM) mw1b[i] = f32_to_bf16(mw1[i]);
    return;
  }
  __shared__ float bufA[2 * D_DIM];
  __shared__ float bufB[2 * D_DIM];
  const int l = blockIdx.x >> 6;
  const int r = blockIdx.x & 63;
  const int j = threadIdx.x;   // 0..255

  if (j < D_DIM) bufA[j] = rel_emb[(l * R_REL + r) * D_DIM + j];
  __syncthreads();
  {
    const float* w = rmw0 + ((size_t)l * 2 * D_DIM + j) * D_DIM;
    float s = rmb0[l * 2 * D_DIM + j];
    for (int k = 0; k < D_DIM; k += 4) {
      float4 wv = *(const float4*)(w + k);
      s += wv.x * bufA[k] + wv.y * bufA[k + 1] + wv.z * bufA[k + 2] + wv.w * bufA[k + 3];
    }
    bufB[j] = fmaxf(s, 0.0f);
  }
  __syncthreads();
  {
    const float* w = rmw1 + ((size_t)l * 2 * D_DIM + j) * 2 * D_DIM;
    float s = rmb1[l * 2 * D_DIM + j];
    for (int k = 0; k < 2 * D_DIM; k += 4) {
      float4 wv = *(const float4*)(w + k);
      s += wv.x * bufB[k] + wv.y * bufB[k + 1] + wv.z * bufB[k + 2] + wv.w * bufB[k + 3];
    }
    __syncthreads();
    bufA[j] = fmaxf(s, 0.0f);
  }
  __syncthreads();
  {
    const float* w = rmw2 + ((size_t)l * 2 * D_DIM + j) * 2 * D_DIM;
    float s = rmb2[l * 2 * D_DIM + j];
    for (int k = 0; k < 2 * D_DIM; k += 4) {
      float4 wv = *(const float4*)(w + k);
      s += wv.x * bufA[k] + wv.y * bufA[k + 1] + wv.z * bufA[k + 2] + wv.w * bufA[k + 3];
    }
    __syncthreads();
    bufB[j] = fmaxf(s, 0.0f);
  }
  __syncthreads();
  {
    const float* w = rmw3 + ((size_t)l * 2 * D_DIM + j) * 2 * D_DIM;
    float s = rmb3[l * 2 * D_DIM + j];
    for (int k = 0; k < 2 * D_DIM; k += 4) {
      float4 wv = *(const float4*)(w + k);
      s += wv.x * bufB[k] + wv.y * bufB[k + 1] + wv.z * bufB[k + 2] + wv.w * bufB[k + 3];
    }
    const int t = l * R_REL + r;
    if (j < D_DIM) {            // gamma col j -> slot (j>>1)*4 + (j&1)
      gbb[t * 256 + (j >> 1) * 4 + (j & 1)] = f2h(s);
    } else {                    // beta col c -> slot (c>>1)*4 + 2 + (c&1)
      int c = j - D_DIM;
      gbb[t * 256 + (c >> 1) * 4 + 2 + (c & 1)] = f2h(s);
    }
  }
}

// ---------------------------------------------------------------------------
// xw = f16( x @ Ww^T + Wb )  (N x 128). bf16 MFMA weights, f16 output.
// (layer 0 only; layer 1's xw is fused into mlp_kernel phase D)
// ---------------------------------------------------------------------------
__global__ __launch_bounds__(256)
void xw_kernel(const float* __restrict__ x,
               const unsigned short* __restrict__ Wwb,  // 128x128 bf16 layer slice
               const float* __restrict__ Wb,            // 128
               unsigned short* __restrict__ xwb) {      // f16 bits out
  __shared__ unsigned short a_lds[32 * LDA];
  const int tid = threadIdx.x;
  const int m0 = blockIdx.x * 32;

  for (int i = tid; i < 1024; i += 256) {
    int row = i >> 5, ch = i & 31;
    float4 v = *(const float4*)&x[(m0 + row) * D_DIM + ch * 4];
    ushort4v s;
    s[0] = f32_to_bf16(v.x); s[1] = f32_to_bf16(v.y);
    s[2] = f32_to_bf16(v.z); s[3] = f32_to_bf16(v.w);
    *(ushort4v*)&a_lds[row * LDA + ch * 4] = s;
  }
  __syncthreads();

  const int wave = tid >> 6, lane = tid & 63;
  const int lrow = lane & 15, quad = lane >> 4;
  const int n0 = wave * 32;

  f32x4 acc[2][2] = {};
  for (int ks = 0; ks < 128; ks += 32) {
    short8 a0 = *(const short8*)&a_lds[lrow * LDA + ks + quad * 8];
    short8 a1 = *(const short8*)&a_lds[(16 + lrow) * LDA + ks + quad * 8];
    short8 b0 = *(const short8*)&Wwb[(n0 + lrow) * D_DIM + ks + quad * 8];
    short8 b1 = *(const short8*)&Wwb[(n0 + 16 + lrow) * D_DIM + ks + quad * 8];
    acc[0][0] = __builtin_amdgcn_mfma_f32_16x16x32_bf16(a0, b0, acc[0][0], 0, 0, 0);
    acc[0][1] = __builtin_amdgcn_mfma_f32_16x16x32_bf16(a0, b1, acc[0][1], 0, 0, 0);
    acc[1][0] = __builtin_amdgcn_mfma_f32_16x16x32_bf16(a1, b0, acc[1][0], 0, 0, 0);
    acc[1][1] = __builtin_amdgcn_mfma_f32_16x16x32_bf16(a1, b1, acc[1][1], 0, 0, 0);
  }

  for (int mt = 0; mt < 2; ++mt)
    for (int nt = 0; nt < 2; ++nt)
      for (int rr = 0; rr < 4; ++rr) {
        int row = mt * 16 + quad * 4 + rr;
        int col = n0 + nt * 16 + lrow;
        xwb[(size_t)(m0 + row) * D_DIM + col] = f2h(acc[mt][nt][rr] + Wb[col]);
      }
}

// ---------------------------------------------------------------------------
// agg: one WAVE per node. Lane l owns cols {2l, 2l+1}; the wave walks the
// node's CSR edge slice; per-edge m = gamma*xw[src]+beta via one __hfma2,
// accumulated in 2 f32 registers. No atomics, no shuffles.
// ---------------------------------------------------------------------------
__global__ __launch_bounds__(256)
void agg_kernel(const int2* __restrict__ edges2, const int* __restrict__ rowptr,
                const float* __restrict__ x, const unsigned short* __restrict__ xwb,
                const unsigned short* __restrict__ gbt, const float* __restrict__ eps,
                unsigned short* __restrict__ o) {
  const int lane = threadIdx.x & 63;
  const int n = __builtin_amdgcn_readfirstlane(blockIdx.x * 4 + (threadIdx.x >> 6));
  const int beg = rowptr[n], end = rowptr[n + 1];

  float acc0 = 0.0f, acc1 = 0.0f;
  int e = beg;
  for (; e + 2 <= end; e += 2) {
    int2 ed0 = edges2[e];
    int2 ed1 = edges2[e + 1];
    __half2 xa = *(const __half2*)&xwb[(size_t)ed0.x * D_DIM + lane * 2];
    __half2 xb = *(const __half2*)&xwb[(size_t)ed1.x * D_DIM + lane * 2];
    uint2 ga = *(const uint2*)&gbt[ed0.y * 256 + lane * 4];   // {g01, b01}
    uint2 gb = *(const uint2*)&gbt[ed1.y * 256 + lane * 4];
    __half2 m0 = __hfma2(u2h(ga.x), xa, u2h(ga.y));
    __half2 m1 = __hfma2(u2h(gb.x), xb, u2h(gb.y));
    float2 f0 = __half22float2(m0);
    float2 f1 = __half22float2(m1);
    acc0 += f0.x + f1.x;
    acc1 += f0.y + f1.y;
  }
  if (e < end) {
    int2 ed0 = edges2[e];
    __half2 xa = *(const __half2*)&xwb[(size_t)ed0.x * D_DIM + lane * 2];
    uint2 ga = *(const uint2*)&gbt[ed0.y * 256 + lane * 4];
    __half2 m0 = __hfma2(u2h(ga.x), xa, u2h(ga.y));
    float2 f0 = __half22float2(m0);
    acc0 += f0.x;
    acc1 += f0.y;
  }

  const float e1v = 1.0f + eps[0];
  float2 xr = *(const float2*)&x[(size_t)n * D_DIM + lane * 2];
  unsigned int w = (unsigned int)f32_to_bf16(e1v * xr.x + acc0)
                 | ((unsigned int)f32_to_bf16(e1v * xr.y + acc1) << 16);
  *(unsigned int*)&o[(size_t)n * D_DIM + lane * 2] = w;
}

// ---------------------------------------------------------------------------
// mlp: block = 128 nodes, 8 waves (512 threads). Weight loads amortized over
// 8 row-tiles (8 MFMA per 16B weight load vs 2 in the 32-row version).
// LDS overlay sequence in ONE 67.6KB buffer (2 blocks/CU):
//   stage: o tile [128][LDA]  ->  B: t tile [128][LDT]  ->  D: y tile [128][LDA]
// B: wave covers 32 cols of t.  C: wave covers 16 cols of y.
// D (optional): wave covers 16 cols of next-layer xw.
// Tail block (rows >= N): staged reads clamped, all global stores guarded.
// ---------------------------------------------------------------------------
__global__ __launch_bounds__(512, 4)
void mlp_kernel(const unsigned short* __restrict__ o,
                const unsigned short* __restrict__ w0b, const float* __restrict__ b0,
                const unsigned short* __restrict__ w1b, const float* __restrict__ b1,
                float* __restrict__ y,
                const unsigned short* __restrict__ WwNb,  // next-layer Ww bf16 (or null)
                const float* __restrict__ WbN,            // next-layer bias
                unsigned short* __restrict__ xwbN) {      // next-layer xw f16 out
  __shared__ unsigned short u_lds[MROWS * LDT];   // 67584 B
  unsigned short* a_lds = u_lds;   // [128][LDA] o tile (stage/B), later y tile (D)
  unsigned short* t_lds = u_lds;   // [128][LDT] t tile (B write / C read)

  const int tid = threadIdx.x;     // 0..511
  const int m0 = blockIdx.x * MROWS;

  // ---- stage o tile (bf16, 16B loads; clamp tail rows)
  for (int i = tid; i < MROWS * 16; i += 512) {
    int row = i >> 4, seg = i & 15;
    int rg = m0 + row; if (rg >= N_NODES) rg = N_NODES - 1;
    *(short8*)&a_lds[row * LDA + seg * 8] =
        *(const short8*)&o[(size_t)rg * D_DIM + seg * 8];
  }
  __syncthreads();

  const int wave = tid >> 6, lane = tid & 63;
  const int lrow = lane & 15, quad = lane >> 4;

  // ---- B: t = relu(o @ w0^T + b0); wave covers cols [wave*32, +32)
  {
    const int n0 = wave * 32;
    f32x4 acc[8][2] = {};
    #pragma unroll
    for (int ks = 0; ks < 128; ks += 32) {
      short8 bf0 = *(const short8*)&w0b[(n0 + lrow) * D_DIM + ks + quad * 8];
      short8 bf1 = *(const short8*)&w0b[(n0 + 16 + lrow) * D_DIM + ks + quad * 8];
      #pragma unroll
      for (int mt = 0; mt < 8; ++mt) {
        short8 a = *(const short8*)&a_lds[(mt * 16 + lrow) * LDA + ks + quad * 8];
        acc[mt][0] = __builtin_amdgcn_mfma_f32_16x16x32_bf16(a, bf0, acc[mt][0], 0, 0, 0);
        acc[mt][1] = __builtin_amdgcn_mfma_f32_16x16x32_bf16(a, bf1, acc[mt][1], 0, 0, 0);
      }
    }
    __syncthreads();   // all waves done reading a_lds
    #pragma unroll
    for (int mt = 0; mt < 8; ++mt)
      #pragma unroll
      for (int nt = 0; nt < 2; ++nt)
        #pragma unroll
        for (int rr = 0; rr < 4; ++rr) {
          int row = mt * 16 + quad * 4 + rr;
          int col = n0 + nt * 16 + lrow;
          float v = acc[mt][nt][rr] + b0[col];
          t_lds[row * LDT + col] = f32_to_bf16(fmaxf(v, 0.0f));
        }
  }
  __syncthreads();

  // ---- C: y = t @ w1^T + b1; wave covers cols [wave*16, +16)
  {
    const int n0 = wave * 16;
    f32x4 acc[8] = {};
    #pragma unroll
    for (int ks = 0; ks < 256; ks += 32) {
      short8 bf = *(const short8*)&w1b[(n0 + lrow) * 2 * D_DIM + ks + quad * 8];
      #pragma unroll
      for (int mt = 0; mt < 8; ++mt) {
        short8 a = *(const short8*)&t_lds[(mt * 16 + lrow) * LDT + ks + quad * 8];
        acc[mt] = __builtin_amdgcn_mfma_f32_16x16x32_bf16(a, bf, acc[mt], 0, 0, 0);
      }
    }
    // y -> global (guarded); keep values in acc for phase D
    #pragma unroll
    for (int mt = 0; mt < 8; ++mt)
      #pragma unroll
      for (int rr = 0; rr < 4; ++rr) {
        int row = mt * 16 + quad * 4 + rr;
        int rg = m0 + row;
        float v = acc[mt][rr] + b1[n0 + lrow];
        acc[mt][rr] = v;
        if (rg < N_NODES) y[(size_t)rg * D_DIM + n0 + lrow] = v;
      }

    if (xwbN) {
      __syncthreads();   // all t reads done -> safe to overlay y tile
      #pragma unroll
      for (int mt = 0; mt < 8; ++mt)
        #pragma unroll
        for (int rr = 0; rr < 4; ++rr) {
          int row = mt * 16 + quad * 4 + rr;
          a_lds[row * LDA + n0 + lrow] = f32_to_bf16(acc[mt][rr]);
        }
    }
  }

  // ---- D (fused next-layer xw): xwbN = f16(y @ WwN^T + WbN)
  if (xwbN) {
    __syncthreads();   // y tile complete
    const int n0 = wave * 16;
    f32x4 acc[8] = {};
    #pragma unroll
    for (int ks = 0; ks < 128; ks += 32) {
      short8 bf = *(const short8*)&WwNb[(n0 + lrow) * D_DIM + ks + quad * 8];
      #pragma unroll
      for (int mt = 0; mt < 8; ++mt) {
        short8 a = *(const short8*)&a_lds[(mt * 16 + lrow) * LDA + ks + quad * 8];
        acc[mt] = __builtin_amdgcn_mfma_f32_16x16x32_bf16(a, bf, acc[mt], 0, 0, 0);
      }
    }
    #pragma unroll
    for (int mt = 0; mt < 8; ++mt)
      #pragma unroll
      for (int rr = 0; rr < 4; ++rr) {
        int row = mt * 16 + quad * 4 + rr;
        int rg = m0 + row;
        if (rg < N_NODES)
          xwbN[(size_t)rg * D_DIM + n0 + lrow] = f2h(acc[mt][rr] + WbN[n0 + lrow]);
      }
  }
}

// ---------------------------------------------------------------------------
extern "C" void kernel_launch(void* const* d_in, const int* in_sizes, int n_in,
                              void* d_out, int out_size, void* d_ws, size_t ws_size,
                              hipStream_t stream) {
  const int*   ei      = (const int*)d_in[0];
  const int*   et      = (const int*)d_in[1];
  const float* embed   = (const float*)d_in[2];
  const float* rel_emb = (const float*)d_in[3];
  const float* rmw0 = (const float*)d_in[4];  const float* rmb0 = (const float*)d_in[5];
  const float* rmw1 = (const float*)d_in[6];  const float* rmb1 = (const float*)d_in[7];
  const float* rmw2 = (const float*)d_in[8];  const float* rmb2 = (const float*)d_in[9];
  const float* rmw3 = (const float*)d_in[10]; const float* rmb3 = (const float*)d_in[11];
  const float* Ww   = (const float*)d_in[12]; const float* Wb   = (const float*)d_in[13];
  const float* mw0  = (const float*)d_in[14]; const float* mb0  = (const float*)d_in[15];
  const float* mw1  = (const float*)d_in[16]; const float* mb1  = (const float*)d_in[17];
  const float* eps  = (const float*)d_in[18];
  float* out = (float*)d_out;

  // workspace layout
  float*          W1   = (float*)d_ws;                          // N*D f32
  unsigned short* xwb  = (unsigned short*)(W1 + (size_t)N_NODES * D_DIM);  // N*D f16
  unsigned short* gbb  = xwb + (size_t)N_NODES * D_DIM;         // L*R*256 f16
  unsigned short* Wwb  = gbb + L_LAYERS * R_REL * 256;          // L*128*128 bf16
  unsigned short* mw0b = Wwb + L_LAYERS * D_DIM * D_DIM;        // L*256*128 bf16
  unsigned short* mw1b = mw0b + L_LAYERS * 2 * D_DIM * D_DIM;   // L*128*256 bf16
  int*   deg     = (int*)(mw1b + L_LAYERS * 2 * D_DIM * D_DIM); // N
  int*   rowptr  = deg + N_NODES;                               // N+1
  int*   cursor  = rowptr + N_NODES + 1;                        // N
  int*   partial = cursor + N_NODES;                            // NBLK_SCAN
  int*   blockoff= partial + NBLK_SCAN;                         // NBLK_SCAN
  int2*  edges2  = (int2*)(blockoff + NBLK_SCAN + 1);           // E int2
  unsigned short* obuf = (unsigned short*)(edges2 + N_EDGES);   // N*D bf16

  // ---- one-shot preprocessing
  hipMemsetAsync(deg, 0, N_NODES * sizeof(int), stream);
  hist_kernel<<<N_EDGES / 256, 256, 0, stream>>>(ei, deg);
  scan_part1<<<NBLK_SCAN, 256, 0, stream>>>(deg, partial);
  scan_part2<<<1, 128, 0, stream>>>(partial, blockoff);
  scan_part3<<<NBLK_SCAN, 256, 0, stream>>>(deg, blockoff, rowptr, cursor);
  scatter_kernel<<<N_EDGES / 256, 256, 0, stream>>>(ei, et, cursor, edges2);
  prep_kernel<<<384, 256, 0, stream>>>(rel_emb, rmw0, rmb0, rmw1, rmb1,
                                       rmw2, rmb2, rmw3, rmb3, gbb,
                                       Ww, mw0, mw1, Wwb, mw0b, mw1b);

  const int gN = N_NODES / 32;        // 3125
  const int gA = N_NODES / 4;         // 25000 (wave per node)

  // ---- layer 0
  xw_kernel<<<gN, 256, 0, stream>>>(embed, Wwb, Wb, xwb);
  agg_kernel<<<gA, 256, 0, stream>>>(edges2, rowptr, embed, xwb, gbb, eps, obuf);
  mlp_kernel<<<GMLP, 512, 0, stream>>>(obuf, mw0b, mb0, mw1b, mb1, W1,
                                       Wwb + D_DIM * D_DIM, Wb + D_DIM, xwb);  // fused xw(L1)

  // ---- layer 1
  agg_kernel<<<gA, 256, 0, stream>>>(edges2, rowptr, W1, xwb,
                                     gbb + R_REL * 256, eps + 1, obuf);
  mlp_kernel<<<GMLP, 512, 0, stream>>>(obuf, mw0b + 2 * D_DIM * D_DIM, mb0 + 2 * D_DIM,
                                       mw1b + 2 * D_DIM * D_DIM, mb1 + D_DIM, out,
                                       nullptr, nullptr, nullptr);
}

// Round 6
// 414.659 us; speedup vs baseline: 2.8468x; 1.0530x over previous
//
#include <hip/hip_runtime.h>
#include <hip/hip_fp16.h>
#include <stdint.h>

#define N_NODES 100000
#define N_EDGES 640000
#define R_REL   64
#define D_DIM   128
#define L_LAYERS 2

#define SCAN_CHUNK 1024
#define NBLK_SCAN ((N_NODES + SCAN_CHUNK - 1) / SCAN_CHUNK)   // 98

#define LDA 136   // bf16 tile stride (128 + 8 pad)
#define LDT 264   // bf16 t-tile stride (256 + 8 pad)
#define LDFY 132  // f32 y-tile stride (128 + 4 pad)
#define MROWS 128 // mlp tile rows
#define GMLP ((N_NODES + MROWS - 1) / MROWS)   // 782

#define HIST_BLKS (N_EDGES / 256)      // 2500
#define XW_BLKS   (N_NODES / 32)       // 3125

typedef __attribute__((ext_vector_type(8))) short   short8;   // 8 bf16 MFMA frag
typedef __attribute__((ext_vector_type(4))) unsigned short ushort4v;
typedef __attribute__((ext_vector_type(4))) float   f32x4;

__device__ __forceinline__ unsigned short f32_to_bf16(float f) {
  union { float f; uint32_t u; } v; v.f = f;
  uint32_t u = v.u;
  u += 0x7fffu + ((u >> 16) & 1u);   // RNE (finite inputs only)
  return (unsigned short)(u >> 16);
}
__device__ __forceinline__ unsigned short f2h(float f) {
  __half h = __float2half(f);
  return __half_as_ushort(h);
}
__device__ __forceinline__ __half2 u2h(unsigned int u) {
  union { unsigned int u; __half2 h; } v; v.u = u; return v.h;
}
__device__ __forceinline__ short8 frag_from_f32(const float* p) {
  short8 r;
  #pragma unroll
  for (int k = 0; k < 8; ++k) r[k] = (short)f32_to_bf16(p[k]);
  return r;
}

// ---------------------------------------------------------------------------
// fused hist (blocks [0,2500)) + prep (blocks [2500,2884))
// prep blocks [0,128): gamma/beta -> packed f16 gbb (lane layout: 4 halfs at
//   t*256+l*4 = {g[2l],g[2l+1],b[2l],b[2l+1]}).
// prep blocks [128,384): weight f32->bf16 conversion.
// ---------------------------------------------------------------------------
__global__ __launch_bounds__(256)
void hist_prep_kernel(const int* __restrict__ ei, int* __restrict__ deg,
                      const float* __restrict__ rel_emb,
                      const float* __restrict__ rmw0, const float* __restrict__ rmb0,
                      const float* __restrict__ rmw1, const float* __restrict__ rmb1,
                      const float* __restrict__ rmw2, const float* __restrict__ rmb2,
                      const float* __restrict__ rmw3, const float* __restrict__ rmb3,
                      unsigned short* __restrict__ gbb,
                      const float* __restrict__ Ww, const float* __restrict__ mw0,
                      const float* __restrict__ mw1,
                      unsigned short* __restrict__ Wwb, unsigned short* __restrict__ mw0b,
                      unsigned short* __restrict__ mw1b) {
  if (blockIdx.x < HIST_BLKS) {
    int idx = blockIdx.x * 256 + threadIdx.x;
    atomicAdd(&deg[ei[N_EDGES + idx]], 1);
    return;
  }
  const int pb = blockIdx.x - HIST_BLKS;   // 0..383
  if (pb >= 128) {
    int i = (pb - 128) * 256 + threadIdx.x;   // 0..65535
    if (i < L_LAYERS * D_DIM * D_DIM)     Wwb[i]  = f32_to_bf16(Ww[i]);
    if (i < L_LAYERS * 2 * D_DIM * D_DIM) mw0b[i] = f32_to_bf16(mw0[i]);
    if (i < L_LAYERS * 2 * D_DIM * D_DIM) mw1b[i] = f32_to_bf16(mw1[i]);
    return;
  }
  __shared__ float bufA[2 * D_DIM];
  __shared__ float bufB[2 * D_DIM];
  const int l = pb >> 6;
  const int r = pb & 63;
  const int j = threadIdx.x;   // 0..255

  if (j < D_DIM) bufA[j] = rel_emb[(l * R_REL + r) * D_DIM + j];
  __syncthreads();
  {
    const float* w = rmw0 + ((size_t)l * 2 * D_DIM + j) * D_DIM;
    float s = rmb0[l * 2 * D_DIM + j];
    for (int k = 0; k < D_DIM; k += 4) {
      float4 wv = *(const float4*)(w + k);
      s += wv.x * bufA[k] + wv.y * bufA[k + 1] + wv.z * bufA[k + 2] + wv.w * bufA[k + 3];
    }
    bufB[j] = fmaxf(s, 0.0f);
  }
  __syncthreads();
  {
    const float* w = rmw1 + ((size_t)l * 2 * D_DIM + j) * 2 * D_DIM;
    float s = rmb1[l * 2 * D_DIM + j];
    for (int k = 0; k < 2 * D_DIM; k += 4) {
      float4 wv = *(const float4*)(w + k);
      s += wv.x * bufB[k] + wv.y * bufB[k + 1] + wv.z * bufB[k + 2] + wv.w * bufB[k + 3];
    }
    __syncthreads();
    bufA[j] = fmaxf(s, 0.0f);
  }
  __syncthreads();
  {
    const float* w = rmw2 + ((size_t)l * 2 * D_DIM + j) * 2 * D_DIM;
    float s = rmb2[l * 2 * D_DIM + j];
    for (int k = 0; k < 2 * D_DIM; k += 4) {
      float4 wv = *(const float4*)(w + k);
      s += wv.x * bufA[k] + wv.y * bufA[k + 1] + wv.z * bufA[k + 2] + wv.w * bufA[k + 3];
    }
    __syncthreads();
    bufB[j] = fmaxf(s, 0.0f);
  }
  __syncthreads();
  {
    const float* w = rmw3 + ((size_t)l * 2 * D_DIM + j) * 2 * D_DIM;
    float s = rmb3[l * 2 * D_DIM + j];
    for (int k = 0; k < 2 * D_DIM; k += 4) {
      float4 wv = *(const float4*)(w + k);
      s += wv.x * bufB[k] + wv.y * bufB[k + 1] + wv.z * bufB[k + 2] + wv.w * bufB[k + 3];
    }
    const int t = l * R_REL + r;
    if (j < D_DIM) {            // gamma col j -> slot (j>>1)*4 + (j&1)
      gbb[t * 256 + (j >> 1) * 4 + (j & 1)] = f2h(s);
    } else {                    // beta col c -> slot (c>>1)*4 + 2 + (c&1)
      int c = j - D_DIM;
      gbb[t * 256 + (c >> 1) * 4 + 2 + (c & 1)] = f2h(s);
    }
  }
}

// ---------------------------------------------------------------------------
// CSR scan: part1 (block sums) then part3b (self-scan of partials + scatter of
// rowptr/cursor) — scan_part2 folded into part3b (98 partials, trivial).
// ---------------------------------------------------------------------------
__global__ __launch_bounds__(256)
void scan_part1(const int* __restrict__ deg, int* __restrict__ partial) {
  __shared__ int lds[256];
  const int b = blockIdx.x, t = threadIdx.x;
  const int base = b * SCAN_CHUNK + t * 4;
  int s = 0;
  for (int k = 0; k < 4; ++k) { int i = base + k; s += (i < N_NODES) ? deg[i] : 0; }
  lds[t] = s; __syncthreads();
  for (int off = 128; off > 0; off >>= 1) {
    if (t < off) lds[t] += lds[t + off];
    __syncthreads();
  }
  if (t == 0) partial[b] = lds[0];
}

__global__ __launch_bounds__(256)
void scan_part3b(const int* __restrict__ deg, const int* __restrict__ partial,
                 int* __restrict__ rowptr, int* __restrict__ cursor) {
  __shared__ int plds[128];
  __shared__ int lds[256];
  const int b = blockIdx.x, t = threadIdx.x;

  // self-scan the 98 block partials (inclusive) -> blockoff = plds[b-1]
  if (t < 128) plds[t] = (t < NBLK_SCAN) ? partial[t] : 0;
  __syncthreads();
  for (int off = 1; off < 128; off <<= 1) {
    int add = (t < 128 && t >= off) ? plds[t - off] : 0;
    __syncthreads();
    if (t < 128) plds[t] += add;
    __syncthreads();
  }
  const int blockoff = (b == 0) ? 0 : plds[b - 1];

  const int base = b * SCAN_CHUNK + t * 4;
  int v[4]; int s = 0;
  for (int k = 0; k < 4; ++k) {
    int i = base + k;
    v[k] = (i < N_NODES) ? deg[i] : 0;
    s += v[k];
  }
  lds[t] = s; __syncthreads();
  for (int off = 1; off < 256; off <<= 1) {
    int add = (t >= off) ? lds[t - off] : 0;
    __syncthreads();
    lds[t] += add;
    __syncthreads();
  }
  int excl = lds[t] - s + blockoff;
  for (int k = 0; k < 4; ++k) {
    int i = base + k;
    if (i < N_NODES) { rowptr[i] = excl; cursor[i] = excl; excl += v[k]; }
  }
  if (b == 0 && t == 0) rowptr[N_NODES] = N_EDGES;
}

// ---------------------------------------------------------------------------
// fused scatter (blocks [0,2500)) + xw layer 0 (blocks [2500,5625))
// xw = f16( x @ Ww^T + Wb )  (N x 128), bf16 MFMA weights.
// ---------------------------------------------------------------------------
__global__ __launch_bounds__(256)
void scatter_xw_kernel(const int* __restrict__ ei, const int* __restrict__ et,
                       int* __restrict__ cursor, int2* __restrict__ edges2,
                       const float* __restrict__ x,
                       const unsigned short* __restrict__ Wwb,
                       const float* __restrict__ Wb,
                       unsigned short* __restrict__ xwb) {
  if (blockIdx.x < HIST_BLKS) {
    int idx = blockIdx.x * 256 + threadIdx.x;
    int dst = ei[N_EDGES + idx];
    int slot = atomicAdd(&cursor[dst], 1);
    edges2[slot] = make_int2(ei[idx], et[idx]);
    return;
  }
  __shared__ unsigned short a_lds[32 * LDA];
  const int tid = threadIdx.x;
  const int m0 = (blockIdx.x - HIST_BLKS) * 32;

  for (int i = tid; i < 1024; i += 256) {
    int row = i >> 5, ch = i & 31;
    float4 v = *(const float4*)&x[(m0 + row) * D_DIM + ch * 4];
    ushort4v s;
    s[0] = f32_to_bf16(v.x); s[1] = f32_to_bf16(v.y);
    s[2] = f32_to_bf16(v.z); s[3] = f32_to_bf16(v.w);
    *(ushort4v*)&a_lds[row * LDA + ch * 4] = s;
  }
  __syncthreads();

  const int wave = tid >> 6, lane = tid & 63;
  const int lrow = lane & 15, quad = lane >> 4;
  const int n0 = wave * 32;

  f32x4 acc[2][2] = {};
  for (int ks = 0; ks < 128; ks += 32) {
    short8 a0 = *(const short8*)&a_lds[lrow * LDA + ks + quad * 8];
    short8 a1 = *(const short8*)&a_lds[(16 + lrow) * LDA + ks + quad * 8];
    short8 b0 = *(const short8*)&Wwb[(n0 + lrow) * D_DIM + ks + quad * 8];
    short8 b1 = *(const short8*)&Wwb[(n0 + 16 + lrow) * D_DIM + ks + quad * 8];
    acc[0][0] = __builtin_amdgcn_mfma_f32_16x16x32_bf16(a0, b0, acc[0][0], 0, 0, 0);
    acc[0][1] = __builtin_amdgcn_mfma_f32_16x16x32_bf16(a0, b1, acc[0][1], 0, 0, 0);
    acc[1][0] = __builtin_amdgcn_mfma_f32_16x16x32_bf16(a1, b0, acc[1][0], 0, 0, 0);
    acc[1][1] = __builtin_amdgcn_mfma_f32_16x16x32_bf16(a1, b1, acc[1][1], 0, 0, 0);
  }

  for (int mt = 0; mt < 2; ++mt)
    for (int nt = 0; nt < 2; ++nt)
      for (int rr = 0; rr < 4; ++rr) {
        int row = mt * 16 + quad * 4 + rr;
        int col = n0 + nt * 16 + lrow;
        xwb[(size_t)(m0 + row) * D_DIM + col] = f2h(acc[mt][nt][rr] + Wb[col]);
      }
}

// ---------------------------------------------------------------------------
// agg: one WAVE per node. Lane l owns cols {2l, 2l+1}; wave walks the node's
// CSR slice; m = gamma*xw[src]+beta (one __hfma2), f32 register accumulation.
// 4-edge unroll: independent loads pipeline the L2/L3 gather latency.
// ---------------------------------------------------------------------------
__global__ __launch_bounds__(256)
void agg_kernel(const int2* __restrict__ edges2, const int* __restrict__ rowptr,
                const float* __restrict__ x, const unsigned short* __restrict__ xwb,
                const unsigned short* __restrict__ gbt, const float* __restrict__ eps,
                unsigned short* __restrict__ o) {
  const int lane = threadIdx.x & 63;
  const int n = __builtin_amdgcn_readfirstlane(blockIdx.x * 4 + (threadIdx.x >> 6));
  const int beg = rowptr[n], end = rowptr[n + 1];

  float acc0 = 0.0f, acc1 = 0.0f;
  int e = beg;
  for (; e + 4 <= end; e += 4) {
    int2 e0 = edges2[e],     e1 = edges2[e + 1];
    int2 e2 = edges2[e + 2], e3 = edges2[e + 3];
    __half2 x0 = *(const __half2*)&xwb[(size_t)e0.x * D_DIM + lane * 2];
    __half2 x1 = *(const __half2*)&xwb[(size_t)e1.x * D_DIM + lane * 2];
    __half2 x2 = *(const __half2*)&xwb[(size_t)e2.x * D_DIM + lane * 2];
    __half2 x3 = *(const __half2*)&xwb[(size_t)e3.x * D_DIM + lane * 2];
    uint2 g0 = *(const uint2*)&gbt[e0.y * 256 + lane * 4];
    uint2 g1 = *(const uint2*)&gbt[e1.y * 256 + lane * 4];
    uint2 g2 = *(const uint2*)&gbt[e2.y * 256 + lane * 4];
    uint2 g3 = *(const uint2*)&gbt[e3.y * 256 + lane * 4];
    __half2 m0 = __hfma2(u2h(g0.x), x0, u2h(g0.y));
    __half2 m1 = __hfma2(u2h(g1.x), x1, u2h(g1.y));
    __half2 m2 = __hfma2(u2h(g2.x), x2, u2h(g2.y));
    __half2 m3 = __hfma2(u2h(g3.x), x3, u2h(g3.y));
    float2 f0 = __half22float2(m0), f1 = __half22float2(m1);
    float2 f2 = __half22float2(m2), f3 = __half22float2(m3);
    acc0 += (f0.x + f1.x) + (f2.x + f3.x);
    acc1 += (f0.y + f1.y) + (f2.y + f3.y);
  }
  if (e + 2 <= end) {
    int2 e0 = edges2[e], e1 = edges2[e + 1];
    __half2 x0 = *(const __half2*)&xwb[(size_t)e0.x * D_DIM + lane * 2];
    __half2 x1 = *(const __half2*)&xwb[(size_t)e1.x * D_DIM + lane * 2];
    uint2 g0 = *(const uint2*)&gbt[e0.y * 256 + lane * 4];
    uint2 g1 = *(const uint2*)&gbt[e1.y * 256 + lane * 4];
    __half2 m0 = __hfma2(u2h(g0.x), x0, u2h(g0.y));
    __half2 m1 = __hfma2(u2h(g1.x), x1, u2h(g1.y));
    float2 f0 = __half22float2(m0), f1 = __half22float2(m1);
    acc0 += f0.x + f1.x;
    acc1 += f0.y + f1.y;
    e += 2;
  }
  if (e < end) {
    int2 e0 = edges2[e];
    __half2 x0 = *(const __half2*)&xwb[(size_t)e0.x * D_DIM + lane * 2];
    uint2 g0 = *(const uint2*)&gbt[e0.y * 256 + lane * 4];
    __half2 m0 = __hfma2(u2h(g0.x), x0, u2h(g0.y));
    float2 f0 = __half22float2(m0);
    acc0 += f0.x;
    acc1 += f0.y;
  }

  const float e1v = 1.0f + eps[0];
  float2 xr = *(const float2*)&x[(size_t)n * D_DIM + lane * 2];
  unsigned int w = (unsigned int)f32_to_bf16(e1v * xr.x + acc0)
                 | ((unsigned int)f32_to_bf16(e1v * xr.y + acc1) << 16);
  *(unsigned int*)&o[(size_t)n * D_DIM + lane * 2] = w;
}

// ---------------------------------------------------------------------------
// mlp: block = 128 nodes, 8 waves. ALL outputs staged through LDS and written
// as full cache lines (float4 / short8 rows) — kills partial-line write
// amplification (R5: WRITE_SIZE 120MB vs ideal 77MB).
// LDS overlay timeline in one 67584 B buffer:
//   o tile [128][136]bf16 -> t tile [128][264]bf16 -> y tile [128][132]f32
//   -> (D) xw tile [128][136]f16
// ---------------------------------------------------------------------------
__global__ __launch_bounds__(512, 4)
void mlp_kernel(const unsigned short* __restrict__ o,
                const unsigned short* __restrict__ w0b, const float* __restrict__ b0,
                const unsigned short* __restrict__ w1b, const float* __restrict__ b1,
                float* __restrict__ y,
                const unsigned short* __restrict__ WwNb,  // next-layer Ww bf16 (or null)
                const float* __restrict__ WbN,            // next-layer bias
                unsigned short* __restrict__ xwbN) {      // next-layer xw f16 out
  __shared__ unsigned short u_lds[MROWS * LDT];   // 67584 B
  unsigned short* a_lds = u_lds;          // [128][LDA] bf16 o tile
  unsigned short* t_lds = u_lds;          // [128][LDT] bf16 t tile
  float*          yf    = (float*)u_lds;  // [128][LDFY] f32 y tile
  unsigned short* xs    = u_lds;          // [128][LDA] f16 xw tile

  const int tid = threadIdx.x;     // 0..511
  const int m0 = blockIdx.x * MROWS;

  // ---- stage o tile (clamp tail rows)
  for (int i = tid; i < MROWS * 16; i += 512) {
    int row = i >> 4, seg = i & 15;
    int rg = m0 + row; if (rg >= N_NODES) rg = N_NODES - 1;
    *(short8*)&a_lds[row * LDA + seg * 8] =
        *(const short8*)&o[(size_t)rg * D_DIM + seg * 8];
  }
  __syncthreads();

  const int wave = tid >> 6, lane = tid & 63;
  const int lrow = lane & 15, quad = lane >> 4;

  // ---- B: t = relu(o @ w0^T + b0); wave covers t cols [wave*32, +32)
  {
    const int n0 = wave * 32;
    f32x4 acc[8][2] = {};
    #pragma unroll
    for (int ks = 0; ks < 128; ks += 32) {
      short8 bf0 = *(const short8*)&w0b[(n0 + lrow) * D_DIM + ks + quad * 8];
      short8 bf1 = *(const short8*)&w0b[(n0 + 16 + lrow) * D_DIM + ks + quad * 8];
      #pragma unroll
      for (int mt = 0; mt < 8; ++mt) {
        short8 a = *(const short8*)&a_lds[(mt * 16 + lrow) * LDA + ks + quad * 8];
        acc[mt][0] = __builtin_amdgcn_mfma_f32_16x16x32_bf16(a, bf0, acc[mt][0], 0, 0, 0);
        acc[mt][1] = __builtin_amdgcn_mfma_f32_16x16x32_bf16(a, bf1, acc[mt][1], 0, 0, 0);
      }
    }
    __syncthreads();   // a dead
    float bb0 = b0[n0 + lrow], bb1 = b0[n0 + 16 + lrow];
    #pragma unroll
    for (int mt = 0; mt < 8; ++mt)
      #pragma unroll
      for (int rr = 0; rr < 4; ++rr) {
        int row = mt * 16 + quad * 4 + rr;
        t_lds[row * LDT + n0 + lrow]      = f32_to_bf16(fmaxf(acc[mt][0][rr] + bb0, 0.0f));
        t_lds[row * LDT + n0 + 16 + lrow] = f32_to_bf16(fmaxf(acc[mt][1][rr] + bb1, 0.0f));
      }
  }
  __syncthreads();

  // ---- C: y = t @ w1^T + b1; wave covers y cols [wave*16, +16)
  {
    const int n0 = wave * 16;
    f32x4 acc[8] = {};
    #pragma unroll
    for (int ks = 0; ks < 256; ks += 32) {
      short8 bf = *(const short8*)&w1b[(n0 + lrow) * 2 * D_DIM + ks + quad * 8];
      #pragma unroll
      for (int mt = 0; mt < 8; ++mt) {
        short8 a = *(const short8*)&t_lds[(mt * 16 + lrow) * LDT + ks + quad * 8];
        acc[mt] = __builtin_amdgcn_mfma_f32_16x16x32_bf16(a, bf, acc[mt], 0, 0, 0);
      }
    }
    __syncthreads();   // t dead
    float bb = b1[n0 + lrow];
    #pragma unroll
    for (int mt = 0; mt < 8; ++mt)
      #pragma unroll
      for (int rr = 0; rr < 4; ++rr) {
        int row = mt * 16 + quad * 4 + rr;
        yf[row * LDFY + n0 + lrow] = acc[mt][rr] + bb;
      }
  }
  __syncthreads();   // y tile complete

  // ---- cooperative y write: full 512B rows, float4 per lane
  for (int i = tid; i < MROWS * 32; i += 512) {
    int row = i >> 5, c4 = i & 31;
    int rg = m0 + row;
    if (rg < N_NODES)
      *(float4*)&y[(size_t)rg * D_DIM + c4 * 4] = *(const float4*)&yf[row * LDFY + c4 * 4];
  }

  // ---- D (fused next-layer xw): xwbN = f16(y @ WwN^T + WbN)
  if (xwbN) {
    const int n0 = wave * 16;
    f32x4 acc[8] = {};
    #pragma unroll
    for (int ks = 0; ks < 128; ks += 32) {
      short8 bf = *(const short8*)&WwNb[(n0 + lrow) * D_DIM + ks + quad * 8];
      #pragma unroll
      for (int mt = 0; mt < 8; ++mt) {
        short8 a = frag_from_f32(&yf[(mt * 16 + lrow) * LDFY + ks + quad * 8]);
        acc[mt] = __builtin_amdgcn_mfma_f32_16x16x32_bf16(a, bf, acc[mt], 0, 0, 0);
      }
    }
    __syncthreads();   // yf dead (also guarantees y-write loop reads done)
    float bb = WbN[n0 + lrow];
    #pragma unroll
    for (int mt = 0; mt < 8; ++mt)
      #pragma unroll
      for (int rr = 0; rr < 4; ++rr) {
        int row = mt * 16 + quad * 4 + rr;
        xs[row * LDA + n0 + lrow] = f2h(acc[mt][rr] + bb);
      }
    __syncthreads();   // xw tile complete
    // cooperative xwb write: full 256B rows, short8 per lane
    for (int i = tid; i < MROWS * 16; i += 512) {
      int row = i >> 4, seg = i & 15;
      int rg = m0 + row;
      if (rg < N_NODES)
        *(short8*)&xwbN[(size_t)rg * D_DIM + seg * 8] = *(const short8*)&xs[row * LDA + seg * 8];
    }
  }
}

// ---------------------------------------------------------------------------
extern "C" void kernel_launch(void* const* d_in, const int* in_sizes, int n_in,
                              void* d_out, int out_size, void* d_ws, size_t ws_size,
                              hipStream_t stream) {
  const int*   ei      = (const int*)d_in[0];
  const int*   et      = (const int*)d_in[1];
  const float* embed   = (const float*)d_in[2];
  const float* rel_emb = (const float*)d_in[3];
  const float* rmw0 = (const float*)d_in[4];  const float* rmb0 = (const float*)d_in[5];
  const float* rmw1 = (const float*)d_in[6];  const float* rmb1 = (const float*)d_in[7];
  const float* rmw2 = (const float*)d_in[8];  const float* rmb2 = (const float*)d_in[9];
  const float* rmw3 = (const float*)d_in[10]; const float* rmb3 = (const float*)d_in[11];
  const float* Ww   = (const float*)d_in[12]; const float* Wb   = (const float*)d_in[13];
  const float* mw0  = (const float*)d_in[14]; const float* mb0  = (const float*)d_in[15];
  const float* mw1  = (const float*)d_in[16]; const float* mb1  = (const float*)d_in[17];
  const float* eps  = (const float*)d_in[18];
  float* out = (float*)d_out;

  // workspace layout
  float*          W1   = (float*)d_ws;                          // N*D f32
  unsigned short* xwb  = (unsigned short*)(W1 + (size_t)N_NODES * D_DIM);  // N*D f16
  unsigned short* gbb  = xwb + (size_t)N_NODES * D_DIM;         // L*R*256 f16
  unsigned short* Wwb  = gbb + L_LAYERS * R_REL * 256;          // L*128*128 bf16
  unsigned short* mw0b = Wwb + L_LAYERS * D_DIM * D_DIM;        // L*256*128 bf16
  unsigned short* mw1b = mw0b + L_LAYERS * 2 * D_DIM * D_DIM;   // L*128*256 bf16
  int*   deg     = (int*)(mw1b + L_LAYERS * 2 * D_DIM * D_DIM); // N
  int*   rowptr  = deg + N_NODES;                               // N+1
  int*   cursor  = rowptr + N_NODES + 1;                        // N
  int*   partial = cursor + N_NODES;                            // NBLK_SCAN
  int*   pad0    = partial + NBLK_SCAN;                         // (spare)
  int2*  edges2  = (int2*)(pad0 + NBLK_SCAN + 1);               // E int2
  unsigned short* obuf = (unsigned short*)(edges2 + N_EDGES);   // N*D bf16

  // ---- preprocessing (hist ∪ prep fused; scan2 folded into scan3b;
  //      scatter ∪ xw(L0) fused)
  hipMemsetAsync(deg, 0, N_NODES * sizeof(int), stream);
  hist_prep_kernel<<<HIST_BLKS + 384, 256, 0, stream>>>(
      ei, deg, rel_emb, rmw0, rmb0, rmw1, rmb1, rmw2, rmb2, rmw3, rmb3, gbb,
      Ww, mw0, mw1, Wwb, mw0b, mw1b);
  scan_part1<<<NBLK_SCAN, 256, 0, stream>>>(deg, partial);
  scan_part3b<<<NBLK_SCAN, 256, 0, stream>>>(deg, partial, rowptr, cursor);
  scatter_xw_kernel<<<HIST_BLKS + XW_BLKS, 256, 0, stream>>>(
      ei, et, cursor, edges2, embed, Wwb, Wb, xwb);

  const int gA = N_NODES / 4;         // 25000 (wave per node)

  // ---- layer 0 (mlp fuses next-layer xw as phase D)
  agg_kernel<<<gA, 256, 0, stream>>>(edges2, rowptr, embed, xwb, gbb, eps, obuf);
  mlp_kernel<<<GMLP, 512, 0, stream>>>(obuf, mw0b, mb0, mw1b, mb1, W1,
                                       Wwb + D_DIM * D_DIM, Wb + D_DIM, xwb);

  // ---- layer 1
  agg_kernel<<<gA, 256, 0, stream>>>(edges2, rowptr, W1, xwb,
                                     gbb + R_REL * 256, eps + 1, obuf);
  mlp_kernel<<<GMLP, 512, 0, stream>>>(obuf, mw0b + 2 * D_DIM * D_DIM, mb0 + 2 * D_DIM,
                                       mw1b + 2 * D_DIM * D_DIM, mb1 + D_DIM, out,
                                       nullptr, nullptr, nullptr);
}